// Round 1
// baseline (1345.979 us; speedup 1.0000x reference)
//
#include <hip/hip_runtime.h>
#include <hip/hip_bf16.h>
#include <math.h>

// ---------------------------------------------------------------------------
// GNN_72103910966081: 4-layer LEConv GNN, N=50000, E=600000, D=128.
// Round 0: correct fp32 baseline.
//   per layer: fused GEMM (a = h@W1+b1 ; d = h@W3+b3 - wsum*(h@W2)) ->
//              atomic scatter of w*a[src] into d -> LN + leaky_relu.
// ---------------------------------------------------------------------------

#define WAVE 64

__device__ inline float wave_reduce_sum(float v) {
    #pragma unroll
    for (int off = 32; off > 0; off >>= 1)
        v += __shfl_xor(v, off, 64);
    return v;
}

// --- per-feature stats over nodes (for input standardization) --------------
__global__ __launch_bounds__(256) void colstats_kernel(
    const float* __restrict__ x, int N, float* __restrict__ sums,
    float* __restrict__ sumsq)
{
    __shared__ float ls[256], lss[256];
    int t = threadIdx.x;
    int f = t & 127;
    int rstart = blockIdx.x * 2 + (t >> 7);
    int stride = gridDim.x * 2;
    float s = 0.f, ss = 0.f;
    for (int r = rstart; r < N; r += stride) {
        float v = x[(size_t)r * 128 + f];
        s += v; ss += v * v;
    }
    ls[t] = s; lss[t] = ss;
    __syncthreads();
    if (t < 128) {
        atomicAdd(&sums[t], ls[t] + ls[t + 128]);
        atomicAdd(&sumsq[t], lss[t] + lss[t + 128]);
    }
}

__global__ void finalize_stats_kernel(const float* __restrict__ sums,
                                      const float* __restrict__ sumsq, int N,
                                      float* __restrict__ mean,
                                      float* __restrict__ rstd)
{
    int f = threadIdx.x;  // 128 threads
    float s = sums[f], ss = sumsq[f];
    float m = s / (float)N;
    float var = (ss - s * s / (float)N) / (float)(N - 1);  // ddof=1 (torch std)
    var = fmaxf(var, 0.f);
    mean[f] = m;
    rstd[f] = 1.f / (sqrtf(var) + 1e-6f);   // ref: / (std + 1e-6)
}

__global__ __launch_bounds__(256) void standardize_kernel(
    const float* __restrict__ x, const float* __restrict__ mean,
    const float* __restrict__ rstd, float* __restrict__ out, long long total)
{
    long long i = (long long)blockIdx.x * blockDim.x + threadIdx.x;
    if (i >= total) return;
    int f = (int)(i & 127);
    out[i] = (x[i] - mean[f]) * rstd[f];
}

// --- wsum[i] = sum of edge weights into node i -----------------------------
__global__ __launch_bounds__(256) void wsum_kernel(
    const int* __restrict__ dst, const float* __restrict__ ew,
    float* __restrict__ wsum, int E)
{
    int e = blockIdx.x * blockDim.x + threadIdx.x;
    if (e >= E) return;
    atomicAdd(&wsum[dst[e]], ew[e]);
}

// --- fused 3-way GEMM: a = h@W1+b1 ; d = h@W3+b3 - wsum*(h@W2) -------------
// block: 256 threads, 32 rows; thread (c = t&127, half = t>>7) computes
// cols c for 16 rows.
__global__ __launch_bounds__(256) void gemm_fused_kernel(
    const float* __restrict__ h, int N,
    const float* __restrict__ W1, const float* __restrict__ b1,
    const float* __restrict__ W2,
    const float* __restrict__ W3, const float* __restrict__ b3,
    const float* __restrict__ wsum,
    float* __restrict__ out_a, float* __restrict__ out_d)
{
    __shared__ float As[32][128];
    int t = threadIdx.x;
    int r0 = blockIdx.x * 32;

    // load A tile (32x128 fp32) as float4, zero-pad past N
    const float4* hv = (const float4*)h;    // row stride = 32 float4
    float4* Asv = (float4*)&As[0][0];
    #pragma unroll
    for (int i = 0; i < 4; ++i) {
        int idx = t + i * 256;              // 0..1023
        int row = idx >> 5;
        int col = idx & 31;
        float4 v = make_float4(0.f, 0.f, 0.f, 0.f);
        if (r0 + row < N) v = hv[(size_t)(r0 + row) * 32 + col];
        Asv[idx] = v;
    }
    __syncthreads();

    int c = t & 127;
    int half = t >> 7;

    float acc1[16], acc2[16], acc3[16];
    #pragma unroll
    for (int r = 0; r < 16; ++r) { acc1[r] = 0.f; acc2[r] = 0.f; acc3[r] = 0.f; }

    for (int k4 = 0; k4 < 32; ++k4) {
        float w1[4], w2[4], w3[4];
        #pragma unroll
        for (int j = 0; j < 4; ++j) {
            int k = k4 * 4 + j;
            w1[j] = W1[k * 128 + c];
            w2[j] = W2[k * 128 + c];
            w3[j] = W3[k * 128 + c];
        }
        #pragma unroll
        for (int r = 0; r < 16; ++r) {
            float4 av = *(const float4*)&As[half * 16 + r][k4 * 4];
            acc1[r] += av.x * w1[0] + av.y * w1[1] + av.z * w1[2] + av.w * w1[3];
            acc2[r] += av.x * w2[0] + av.y * w2[1] + av.z * w2[2] + av.w * w2[3];
            acc3[r] += av.x * w3[0] + av.y * w3[1] + av.z * w3[2] + av.w * w3[3];
        }
    }

    float bb1 = b1[c], bb3 = b3[c];
    #pragma unroll
    for (int r = 0; r < 16; ++r) {
        int row = r0 + half * 16 + r;
        if (row < N) {
            float ws = wsum[row];
            out_a[(size_t)row * 128 + c] = acc1[r] + bb1;
            out_d[(size_t)row * 128 + c] = acc3[r] + bb3 - ws * acc2[r];
        }
    }
}

// --- scatter: agg[dst] += w * a[src], one thread per (edge, feature) -------
__global__ __launch_bounds__(256) void scatter_feat_kernel(
    const int* __restrict__ src, const int* __restrict__ dst,
    const float* __restrict__ ew, const float* __restrict__ a,
    float* __restrict__ agg, long long total)
{
    long long idx = (long long)blockIdx.x * blockDim.x + threadIdx.x;
    if (idx >= total) return;
    int e = (int)(idx >> 7);
    int f = (int)(idx & 127);
    int s = src[e], d = dst[e];
    float w = ew[e];
    atomicAdd(&agg[(size_t)d * 128 + f], w * a[(size_t)s * 128 + f]);
}

// --- LayerNorm + leaky_relu(0.1), one wave per node ------------------------
__global__ __launch_bounds__(256) void ln_leaky_kernel(
    const float* __restrict__ in, const float* __restrict__ g,
    const float* __restrict__ beta, float* __restrict__ out, int N)
{
    int wave = threadIdx.x >> 6;
    int lane = threadIdx.x & 63;
    int node = blockIdx.x * 4 + wave;
    if (node >= N) return;
    const float* row = in + (size_t)node * 128;
    float v0 = row[lane], v1 = row[lane + 64];
    float s  = wave_reduce_sum(v0 + v1);
    float ss = wave_reduce_sum(v0 * v0 + v1 * v1);
    float mean = s * (1.f / 128.f);
    float var = ss * (1.f / 128.f) - mean * mean;          // biased (ddof=0)
    float rstd = rsqrtf(var + 1e-5f);
    float o0 = (v0 - mean) * rstd * g[lane] + beta[lane];
    float o1 = (v1 - mean) * rstd * g[lane + 64] + beta[lane + 64];
    o0 = o0 >= 0.f ? o0 : 0.1f * o0;
    o1 = o1 >= 0.f ? o1 : 0.1f * o1;
    out[(size_t)node * 128 + lane] = o0;
    out[(size_t)node * 128 + lane + 64] = o1;
}

// --- output layer (D_OUT = 1): three dot products per node -----------------
__global__ __launch_bounds__(256) void out_gemv_kernel(
    const float* __restrict__ h, int N,
    const float* __restrict__ W1, const float* __restrict__ b1,
    const float* __restrict__ W2,
    const float* __restrict__ W3, const float* __restrict__ b3,
    const float* __restrict__ wsum,
    float* __restrict__ a1, float* __restrict__ dpart)
{
    int wave = threadIdx.x >> 6;
    int lane = threadIdx.x & 63;
    int node = blockIdx.x * 4 + wave;
    if (node >= N) return;
    const float* row = h + (size_t)node * 128;
    float h0 = row[lane], h1 = row[lane + 64];
    float s1 = wave_reduce_sum(h0 * W1[lane] + h1 * W1[lane + 64]);
    float s2 = wave_reduce_sum(h0 * W2[lane] + h1 * W2[lane + 64]);
    float s3 = wave_reduce_sum(h0 * W3[lane] + h1 * W3[lane + 64]);
    if (lane == 0) {
        a1[node] = s1 + b1[0];
        dpart[node] = s3 + b3[0] - wsum[node] * s2;
    }
}

__global__ __launch_bounds__(256) void scatter_scalar_kernel(
    const int* __restrict__ src, const int* __restrict__ dst,
    const float* __restrict__ ew, const float* __restrict__ a1,
    float* __restrict__ outacc, int E)
{
    int e = blockIdx.x * blockDim.x + threadIdx.x;
    if (e >= E) return;
    atomicAdd(&outacc[dst[e]], ew[e] * a1[src[e]]);
}

__global__ __launch_bounds__(256) void sigmoid_kernel(
    const float* __restrict__ in, float* __restrict__ out, int N)
{
    int i = blockIdx.x * blockDim.x + threadIdx.x;
    if (i >= N) return;
    out[i] = 1.f / (1.f + expf(-in[i]));
}

// ---------------------------------------------------------------------------
extern "C" void kernel_launch(void* const* d_in, const int* in_sizes, int n_in,
                              void* d_out, int out_size, void* d_ws, size_t ws_size,
                              hipStream_t stream)
{
    const float* x     = (const float*)d_in[0];
    const float* ew    = (const float*)d_in[1];
    const float* W1_in = (const float*)d_in[2];
    const float* b1_in = (const float*)d_in[3];
    const float* W2_in = (const float*)d_in[4];
    const float* W3_in = (const float*)d_in[5];
    const float* b3_in = (const float*)d_in[6];
    const float* W1_h  = (const float*)d_in[7];
    const float* b1_h  = (const float*)d_in[8];
    const float* W2_h  = (const float*)d_in[9];
    const float* W3_h  = (const float*)d_in[10];
    const float* b3_h  = (const float*)d_in[11];
    const float* W1_o  = (const float*)d_in[12];
    const float* b1_o  = (const float*)d_in[13];
    const float* W2_o  = (const float*)d_in[14];
    const float* W3_o  = (const float*)d_in[15];
    const float* b3_o  = (const float*)d_in[16];
    const float* g1    = (const float*)d_in[17];
    const float* beta1 = (const float*)d_in[18];
    const float* g2    = (const float*)d_in[19];
    const float* beta2 = (const float*)d_in[20];
    const int*   eidx  = (const int*)d_in[21];

    const int N = in_sizes[0] / 128;
    const int E = in_sizes[1];
    const int* srcp = eidx;
    const int* dstp = eidx + E;

    // workspace layout (floats)
    float* ws      = (float*)d_ws;
    float* buf_h   = ws;                          // N*128
    float* buf_a   = buf_h  + (size_t)N * 128;    // N*128
    float* buf_agg = buf_a  + (size_t)N * 128;    // N*128
    float* stats   = buf_agg + (size_t)N * 128;   // 256 (sums, sumsq)
    float* meanp   = stats + 256;                 // 128
    float* rstdp   = meanp + 128;                 // 128
    float* wsum    = rstdp + 128;                 // N
    float* a1      = wsum + N;                    // N
    float* outacc  = a1 + N;                      // N

    const long long totNF = (long long)N * 128;
    const long long totEF = (long long)E * 128;
    const int nodeWaveBlocks = (N + 3) / 4;

    // zero accumulators (ws is poisoned 0xAA each call)
    hipMemsetAsync(stats, 0, 256 * sizeof(float), stream);
    hipMemsetAsync(wsum, 0, (size_t)N * sizeof(float), stream);

    // input standardization
    colstats_kernel<<<256, 256, 0, stream>>>(x, N, stats, stats + 128);
    finalize_stats_kernel<<<1, 128, 0, stream>>>(stats, stats + 128, N, meanp, rstdp);
    standardize_kernel<<<(int)((totNF + 255) / 256), 256, 0, stream>>>(x, meanp, rstdp, buf_h, totNF);

    // wsum (layer-invariant)
    wsum_kernel<<<(E + 255) / 256, 256, 0, stream>>>(dstp, ew, wsum, E);

    const int gemmBlocks = (N + 31) / 32;
    const int scatBlocks = (int)((totEF + 255) / 256);

    // layer 1 (input LEConv) + LN(g1) + leaky
    gemm_fused_kernel<<<gemmBlocks, 256, 0, stream>>>(buf_h, N, W1_in, b1_in, W2_in, W3_in, b3_in, wsum, buf_a, buf_agg);
    scatter_feat_kernel<<<scatBlocks, 256, 0, stream>>>(srcp, dstp, ew, buf_a, buf_agg, totEF);
    ln_leaky_kernel<<<nodeWaveBlocks, 256, 0, stream>>>(buf_agg, g1, beta1, buf_h, N);

    // layers 2..3 (inner LEConv, number_of_layers=4 -> 2 iterations) + LN(g2)
    for (int l = 0; l < 2; ++l) {
        gemm_fused_kernel<<<gemmBlocks, 256, 0, stream>>>(buf_h, N, W1_h, b1_h, W2_h, W3_h, b3_h, wsum, buf_a, buf_agg);
        scatter_feat_kernel<<<scatBlocks, 256, 0, stream>>>(srcp, dstp, ew, buf_a, buf_agg, totEF);
        ln_leaky_kernel<<<nodeWaveBlocks, 256, 0, stream>>>(buf_agg, g2, beta2, buf_h, N);
    }

    // output LEConv (D_OUT=1) + sigmoid
    out_gemv_kernel<<<nodeWaveBlocks, 256, 0, stream>>>(buf_h, N, W1_o, b1_o, W2_o, W3_o, b3_o, wsum, a1, outacc);
    scatter_scalar_kernel<<<(E + 255) / 256, 256, 0, stream>>>(srcp, dstp, ew, a1, outacc, E);
    sigmoid_kernel<<<(N + 255) / 256, 256, 0, stream>>>(outacc, (float*)d_out, N);
}

// Round 2
// 715.709 us; speedup vs baseline: 1.8806x; 1.8806x over previous
//
#include <hip/hip_runtime.h>
#include <hip/hip_bf16.h>
#include <math.h>

// ---------------------------------------------------------------------------
// GNN_72103910966081: 4-layer LEConv GNN, N=50000, E=600000, D=128.
// Round 1: replace atomic scatter (300 MB HBM atomic writes/layer) with
// per-call CSR build + gather aggregation fused with +dense, LN, leaky_relu.
// ---------------------------------------------------------------------------

__device__ inline float wave_reduce_sum(float v) {
    #pragma unroll
    for (int off = 32; off > 0; off >>= 1)
        v += __shfl_xor(v, off, 64);
    return v;
}

// ===================== CSR build =====================

__global__ __launch_bounds__(256) void hist_kernel(
    const int* __restrict__ dst, int* __restrict__ deg, int E)
{
    int e = blockIdx.x * 256 + threadIdx.x;
    if (e < E) atomicAdd(&deg[dst[e]], 1);
}

// each block scans 1024 elements (4/thread)
__global__ __launch_bounds__(256) void scan_pass1(
    const int* __restrict__ deg, int N, int* __restrict__ partial)
{
    __shared__ int sh[256];
    int t = threadIdx.x;
    int base = blockIdx.x * 1024 + t * 4;
    int s = 0;
    #pragma unroll
    for (int i = 0; i < 4; ++i) { int idx = base + i; if (idx < N) s += deg[idx]; }
    sh[t] = s; __syncthreads();
    for (int off = 128; off > 0; off >>= 1) {
        if (t < off) sh[t] += sh[t + off];
        __syncthreads();
    }
    if (t == 0) partial[blockIdx.x] = sh[0];
}

__global__ __launch_bounds__(256) void scan_pass2(int* __restrict__ partial, int nb)
{
    __shared__ int sh[256];
    int t = threadIdx.x;
    sh[t] = (t < nb) ? partial[t] : 0;
    __syncthreads();
    for (int off = 1; off < 256; off <<= 1) {
        int x = sh[t];
        if (t >= off) x += sh[t - off];
        __syncthreads();
        sh[t] = x;
        __syncthreads();
    }
    if (t < nb) partial[t] = (t > 0) ? sh[t - 1] : 0;   // exclusive
}

__global__ __launch_bounds__(256) void scan_pass3(
    const int* __restrict__ deg, int N, const int* __restrict__ partial,
    int* __restrict__ rowptr, int* __restrict__ fill, int E)
{
    __shared__ int sh[256];
    int t = threadIdx.x;
    int base = blockIdx.x * 1024 + t * 4;
    int v[4]; int s = 0;
    #pragma unroll
    for (int i = 0; i < 4; ++i) { int idx = base + i; v[i] = (idx < N) ? deg[idx] : 0; s += v[i]; }
    sh[t] = s; __syncthreads();
    for (int off = 1; off < 256; off <<= 1) {
        int x = sh[t];
        if (t >= off) x += sh[t - off];
        __syncthreads();
        sh[t] = x;
        __syncthreads();
    }
    int off0 = partial[blockIdx.x] + ((t > 0) ? sh[t - 1] : 0);
    #pragma unroll
    for (int i = 0; i < 4; ++i) {
        int idx = base + i;
        if (idx < N) { rowptr[idx] = off0; fill[idx] = off0; off0 += v[i]; }
    }
    if (blockIdx.x == 0 && t == 0) rowptr[N] = E;
}

__global__ __launch_bounds__(256) void csr_fill_kernel(
    const int* __restrict__ src, const int* __restrict__ dst,
    const float* __restrict__ ew, int* __restrict__ fill,
    int2* __restrict__ csr, int E)
{
    int e = blockIdx.x * 256 + threadIdx.x;
    if (e >= E) return;
    int d = dst[e];
    int pos = atomicAdd(&fill[d], 1);
    csr[pos] = make_int2(src[e], __float_as_int(ew[e]));
}

__global__ __launch_bounds__(256) void wsum_csr_kernel(
    const int* __restrict__ rowptr, const int2* __restrict__ csr,
    float* __restrict__ wsum, int N)
{
    int n = blockIdx.x * 256 + threadIdx.x;
    if (n >= N) return;
    int b = rowptr[n], en = rowptr[n + 1];
    float s = 0.f;
    for (int e = b; e < en; ++e) s += __int_as_float(csr[e].y);
    wsum[n] = s;
}

// ===================== input standardization =====================

__global__ __launch_bounds__(256) void colstats_kernel(
    const float* __restrict__ x, int N, float* __restrict__ sums,
    float* __restrict__ sumsq)
{
    __shared__ float ls[256], lss[256];
    int t = threadIdx.x;
    int f = t & 127;
    int rstart = blockIdx.x * 2 + (t >> 7);
    int stride = gridDim.x * 2;
    float s = 0.f, ss = 0.f;
    for (int r = rstart; r < N; r += stride) {
        float v = x[(size_t)r * 128 + f];
        s += v; ss += v * v;
    }
    ls[t] = s; lss[t] = ss;
    __syncthreads();
    if (t < 128) {
        atomicAdd(&sums[t], ls[t] + ls[t + 128]);
        atomicAdd(&sumsq[t], lss[t] + lss[t + 128]);
    }
}

__global__ void finalize_stats_kernel(const float* __restrict__ sums,
                                      const float* __restrict__ sumsq, int N,
                                      float* __restrict__ mean,
                                      float* __restrict__ rstd)
{
    int f = threadIdx.x;  // 128 threads
    float s = sums[f], ss = sumsq[f];
    float m = s / (float)N;
    float var = (ss - s * s / (float)N) / (float)(N - 1);  // ddof=1
    var = fmaxf(var, 0.f);
    mean[f] = m;
    rstd[f] = 1.f / (sqrtf(var) + 1e-6f);
}

__global__ __launch_bounds__(256) void standardize_kernel(
    const float* __restrict__ x, const float* __restrict__ mean,
    const float* __restrict__ rstd, float* __restrict__ out, long long total)
{
    long long i = (long long)blockIdx.x * blockDim.x + threadIdx.x;
    if (i >= total) return;
    int f = (int)(i & 127);
    out[i] = (x[i] - mean[f]) * rstd[f];
}

// ===================== fused 3-way GEMM =====================
// a = h@W1+b1 ; d = h@W3+b3 - wsum*(h@W2)

__global__ __launch_bounds__(256) void gemm_fused_kernel(
    const float* __restrict__ h, int N,
    const float* __restrict__ W1, const float* __restrict__ b1,
    const float* __restrict__ W2,
    const float* __restrict__ W3, const float* __restrict__ b3,
    const float* __restrict__ wsum,
    float* __restrict__ out_a, float* __restrict__ out_d)
{
    __shared__ float As[32][128];
    int t = threadIdx.x;
    int r0 = blockIdx.x * 32;

    const float4* hv = (const float4*)h;
    float4* Asv = (float4*)&As[0][0];
    #pragma unroll
    for (int i = 0; i < 4; ++i) {
        int idx = t + i * 256;
        int row = idx >> 5;
        int col = idx & 31;
        float4 v = make_float4(0.f, 0.f, 0.f, 0.f);
        if (r0 + row < N) v = hv[(size_t)(r0 + row) * 32 + col];
        Asv[idx] = v;
    }
    __syncthreads();

    int c = t & 127;
    int half = t >> 7;

    float acc1[16], acc2[16], acc3[16];
    #pragma unroll
    for (int r = 0; r < 16; ++r) { acc1[r] = 0.f; acc2[r] = 0.f; acc3[r] = 0.f; }

    for (int k4 = 0; k4 < 32; ++k4) {
        float w1[4], w2[4], w3[4];
        #pragma unroll
        for (int j = 0; j < 4; ++j) {
            int k = k4 * 4 + j;
            w1[j] = W1[k * 128 + c];
            w2[j] = W2[k * 128 + c];
            w3[j] = W3[k * 128 + c];
        }
        #pragma unroll
        for (int r = 0; r < 16; ++r) {
            float4 av = *(const float4*)&As[half * 16 + r][k4 * 4];
            acc1[r] += av.x * w1[0] + av.y * w1[1] + av.z * w1[2] + av.w * w1[3];
            acc2[r] += av.x * w2[0] + av.y * w2[1] + av.z * w2[2] + av.w * w2[3];
            acc3[r] += av.x * w3[0] + av.y * w3[1] + av.z * w3[2] + av.w * w3[3];
        }
    }

    float bb1 = b1[c], bb3 = b3[c];
    #pragma unroll
    for (int r = 0; r < 16; ++r) {
        int row = r0 + half * 16 + r;
        if (row < N) {
            float ws = wsum[row];
            out_a[(size_t)row * 128 + c] = acc1[r] + bb1;
            out_d[(size_t)row * 128 + c] = acc3[r] + bb3 - ws * acc2[r];
        }
    }
}

// ===================== fused gather + LN + leaky =====================
// out[n] = leaky(LN(sum_e w_e*a[src_e] + d[n]))   — one wave per node

__global__ __launch_bounds__(256) void aggregate_ln_kernel(
    const int* __restrict__ rowptr, const int2* __restrict__ csr,
    const float* __restrict__ a, const float* __restrict__ d,
    const float* __restrict__ g, const float* __restrict__ beta,
    float* __restrict__ out, int N)
{
    int wave = threadIdx.x >> 6;
    int lane = threadIdx.x & 63;
    int node = blockIdx.x * 4 + wave;
    if (node >= N) return;
    int b = rowptr[node], en = rowptr[node + 1];
    float acc0 = 0.f, acc1 = 0.f;
    const float2* av = (const float2*)a;
    int e = b;
    for (; e + 1 < en; e += 2) {
        int2 p0 = csr[e], p1 = csr[e + 1];
        float2 v0 = av[(size_t)p0.x * 64 + lane];
        float2 v1 = av[(size_t)p1.x * 64 + lane];
        float w0 = __int_as_float(p0.y), w1 = __int_as_float(p1.y);
        acc0 += w0 * v0.x + w1 * v1.x;
        acc1 += w0 * v0.y + w1 * v1.y;
    }
    if (e < en) {
        int2 p = csr[e];
        float2 v = av[(size_t)p.x * 64 + lane];
        float w = __int_as_float(p.y);
        acc0 += w * v.x;
        acc1 += w * v.y;
    }
    float2 dv = ((const float2*)d)[(size_t)node * 64 + lane];
    float v0 = acc0 + dv.x, v1 = acc1 + dv.y;
    float s  = wave_reduce_sum(v0 + v1);
    float ss = wave_reduce_sum(v0 * v0 + v1 * v1);
    float mean = s * (1.f / 128.f);
    float var = ss * (1.f / 128.f) - mean * mean;
    float rstd = rsqrtf(var + 1e-5f);
    float2 gv = ((const float2*)g)[lane];
    float2 bv = ((const float2*)beta)[lane];
    float o0 = (v0 - mean) * rstd * gv.x + bv.x;
    float o1 = (v1 - mean) * rstd * gv.y + bv.y;
    o0 = o0 >= 0.f ? o0 : 0.1f * o0;
    o1 = o1 >= 0.f ? o1 : 0.1f * o1;
    ((float2*)out)[(size_t)node * 64 + lane] = make_float2(o0, o1);
}

// ===================== output layer (D_OUT=1) =====================

__global__ __launch_bounds__(256) void out_gemv_kernel(
    const float* __restrict__ h, int N,
    const float* __restrict__ W1, const float* __restrict__ b1,
    const float* __restrict__ W2,
    const float* __restrict__ W3, const float* __restrict__ b3,
    const float* __restrict__ wsum,
    float* __restrict__ a1, float* __restrict__ dpart)
{
    int wave = threadIdx.x >> 6;
    int lane = threadIdx.x & 63;
    int node = blockIdx.x * 4 + wave;
    if (node >= N) return;
    const float* row = h + (size_t)node * 128;
    float h0 = row[lane], h1 = row[lane + 64];
    float s1 = wave_reduce_sum(h0 * W1[lane] + h1 * W1[lane + 64]);
    float s2 = wave_reduce_sum(h0 * W2[lane] + h1 * W2[lane + 64]);
    float s3 = wave_reduce_sum(h0 * W3[lane] + h1 * W3[lane + 64]);
    if (lane == 0) {
        a1[node] = s1 + b1[0];
        dpart[node] = s3 + b3[0] - wsum[node] * s2;
    }
}

__global__ __launch_bounds__(256) void gather_out_kernel(
    const int* __restrict__ rowptr, const int2* __restrict__ csr,
    const float* __restrict__ a1, const float* __restrict__ dpart,
    float* __restrict__ out, int N)
{
    int n = blockIdx.x * 256 + threadIdx.x;
    if (n >= N) return;
    int b = rowptr[n], en = rowptr[n + 1];
    float s = dpart[n];
    for (int e = b; e < en; ++e) {
        int2 p = csr[e];
        s += __int_as_float(p.y) * a1[p.x];
    }
    out[n] = 1.f / (1.f + expf(-s));
}

// ---------------------------------------------------------------------------
extern "C" void kernel_launch(void* const* d_in, const int* in_sizes, int n_in,
                              void* d_out, int out_size, void* d_ws, size_t ws_size,
                              hipStream_t stream)
{
    const float* x     = (const float*)d_in[0];
    const float* ew    = (const float*)d_in[1];
    const float* W1_in = (const float*)d_in[2];
    const float* b1_in = (const float*)d_in[3];
    const float* W2_in = (const float*)d_in[4];
    const float* W3_in = (const float*)d_in[5];
    const float* b3_in = (const float*)d_in[6];
    const float* W1_h  = (const float*)d_in[7];
    const float* b1_h  = (const float*)d_in[8];
    const float* W2_h  = (const float*)d_in[9];
    const float* W3_h  = (const float*)d_in[10];
    const float* b3_h  = (const float*)d_in[11];
    const float* W1_o  = (const float*)d_in[12];
    const float* b1_o  = (const float*)d_in[13];
    const float* W2_o  = (const float*)d_in[14];
    const float* W3_o  = (const float*)d_in[15];
    const float* b3_o  = (const float*)d_in[16];
    const float* g1    = (const float*)d_in[17];
    const float* beta1 = (const float*)d_in[18];
    const float* g2    = (const float*)d_in[19];
    const float* beta2 = (const float*)d_in[20];
    const int*   eidx  = (const int*)d_in[21];

    const int N = in_sizes[0] / 128;
    const int E = in_sizes[1];
    const int* srcp = eidx;
    const int* dstp = eidx + E;

    // ---- workspace carve-out (256B-aligned chunks) ----
    size_t off = 0;
    auto carve = [&](size_t nbytes) -> void* {
        void* p = (char*)d_ws + off;
        off += (nbytes + 255) & ~(size_t)255;
        return p;
    };
    float* buf_h  = (float*)carve((size_t)N * 128 * 4);
    float* buf_a  = (float*)carve((size_t)N * 128 * 4);
    float* buf_d  = (float*)carve((size_t)N * 128 * 4);
    int2*  csr    = (int2*) carve((size_t)E * 8);
    int*   deg    = (int*)  carve((size_t)N * 4);
    int*   rowptr = (int*)  carve((size_t)(N + 1) * 4);
    int*   fill   = (int*)  carve((size_t)N * 4);
    int*   partial= (int*)  carve(256 * 4);
    float* stats  = (float*)carve(256 * 4);
    float* meanp  = (float*)carve(128 * 4);
    float* rstdp  = (float*)carve(128 * 4);
    float* wsum   = (float*)carve((size_t)N * 4);
    float* a1     = (float*)carve((size_t)N * 4);
    float* dpart  = (float*)carve((size_t)N * 4);

    const long long totNF = (long long)N * 128;
    const int nodeWaveBlocks = (N + 3) / 4;
    const int eBlocks = (E + 255) / 256;
    const int nBlocks = (N + 255) / 256;
    const int nb = (N + 1023) / 1024;   // scan blocks (49 for N=50000, <=256)

    hipMemsetAsync(deg, 0, (size_t)N * 4, stream);
    hipMemsetAsync(stats, 0, 256 * 4, stream);

    // ---- CSR build ----
    hist_kernel<<<eBlocks, 256, 0, stream>>>(dstp, deg, E);
    scan_pass1<<<nb, 256, 0, stream>>>(deg, N, partial);
    scan_pass2<<<1, 256, 0, stream>>>(partial, nb);
    scan_pass3<<<nb, 256, 0, stream>>>(deg, N, partial, rowptr, fill, E);
    csr_fill_kernel<<<eBlocks, 256, 0, stream>>>(srcp, dstp, ew, fill, csr, E);
    wsum_csr_kernel<<<nBlocks, 256, 0, stream>>>(rowptr, csr, wsum, N);

    // ---- input standardization ----
    colstats_kernel<<<256, 256, 0, stream>>>(x, N, stats, stats + 128);
    finalize_stats_kernel<<<1, 128, 0, stream>>>(stats, stats + 128, N, meanp, rstdp);
    standardize_kernel<<<(int)((totNF + 255) / 256), 256, 0, stream>>>(x, meanp, rstdp, buf_h, totNF);

    const int gemmBlocks = (N + 31) / 32;

    // ---- layer 1 ----
    gemm_fused_kernel<<<gemmBlocks, 256, 0, stream>>>(buf_h, N, W1_in, b1_in, W2_in, W3_in, b3_in, wsum, buf_a, buf_d);
    aggregate_ln_kernel<<<nodeWaveBlocks, 256, 0, stream>>>(rowptr, csr, buf_a, buf_d, g1, beta1, buf_h, N);

    // ---- layers 2..3 ----
    for (int l = 0; l < 2; ++l) {
        gemm_fused_kernel<<<gemmBlocks, 256, 0, stream>>>(buf_h, N, W1_h, b1_h, W2_h, W3_h, b3_h, wsum, buf_a, buf_d);
        aggregate_ln_kernel<<<nodeWaveBlocks, 256, 0, stream>>>(rowptr, csr, buf_a, buf_d, g2, beta2, buf_h, N);
    }

    // ---- output layer ----
    out_gemv_kernel<<<nodeWaveBlocks, 256, 0, stream>>>(buf_h, N, W1_o, b1_o, W2_o, W3_o, b3_o, wsum, a1, dpart);
    gather_out_kernel<<<nBlocks, 256, 0, stream>>>(rowptr, csr, a1, dpart, (float*)d_out, N);
}

// Round 3
// 548.596 us; speedup vs baseline: 2.4535x; 1.3046x over previous
//
#include <hip/hip_runtime.h>
#include <hip/hip_bf16.h>
#include <math.h>

// ---------------------------------------------------------------------------
// GNN_72103910966081: 4-layer LEConv GNN, N=50000, E=600000, D=128.
// Round 2: MFMA (fp16) fused GEMM  [N,128]x[128,384] via mfma_f32_16x16x32_f16;
//          fp16 h/a buffers halve aggregation gather traffic. d stays fp32.
// ---------------------------------------------------------------------------

typedef _Float16 f16x8 __attribute__((ext_vector_type(8)));
typedef _Float16 f16x2 __attribute__((ext_vector_type(2)));
typedef float f32x4 __attribute__((ext_vector_type(4)));

__device__ inline float wave_reduce_sum(float v) {
    #pragma unroll
    for (int off = 32; off > 0; off >>= 1)
        v += __shfl_xor(v, off, 64);
    return v;
}

// ===================== CSR build =====================

__global__ __launch_bounds__(256) void hist_kernel(
    const int* __restrict__ dst, int* __restrict__ deg, int E)
{
    int e = blockIdx.x * 256 + threadIdx.x;
    if (e < E) atomicAdd(&deg[dst[e]], 1);
}

__global__ __launch_bounds__(256) void scan_pass1(
    const int* __restrict__ deg, int N, int* __restrict__ partial)
{
    __shared__ int sh[256];
    int t = threadIdx.x;
    int base = blockIdx.x * 1024 + t * 4;
    int s = 0;
    #pragma unroll
    for (int i = 0; i < 4; ++i) { int idx = base + i; if (idx < N) s += deg[idx]; }
    sh[t] = s; __syncthreads();
    for (int off = 128; off > 0; off >>= 1) {
        if (t < off) sh[t] += sh[t + off];
        __syncthreads();
    }
    if (t == 0) partial[blockIdx.x] = sh[0];
}

__global__ __launch_bounds__(256) void scan_pass2(int* __restrict__ partial, int nb)
{
    __shared__ int sh[256];
    int t = threadIdx.x;
    sh[t] = (t < nb) ? partial[t] : 0;
    __syncthreads();
    for (int off = 1; off < 256; off <<= 1) {
        int x = sh[t];
        if (t >= off) x += sh[t - off];
        __syncthreads();
        sh[t] = x;
        __syncthreads();
    }
    if (t < nb) partial[t] = (t > 0) ? sh[t - 1] : 0;   // exclusive
}

__global__ __launch_bounds__(256) void scan_pass3(
    const int* __restrict__ deg, int N, const int* __restrict__ partial,
    int* __restrict__ rowptr, int* __restrict__ fill, int E)
{
    __shared__ int sh[256];
    int t = threadIdx.x;
    int base = blockIdx.x * 1024 + t * 4;
    int v[4]; int s = 0;
    #pragma unroll
    for (int i = 0; i < 4; ++i) { int idx = base + i; v[i] = (idx < N) ? deg[idx] : 0; s += v[i]; }
    sh[t] = s; __syncthreads();
    for (int off = 1; off < 256; off <<= 1) {
        int x = sh[t];
        if (t >= off) x += sh[t - off];
        __syncthreads();
        sh[t] = x;
        __syncthreads();
    }
    int off0 = partial[blockIdx.x] + ((t > 0) ? sh[t - 1] : 0);
    #pragma unroll
    for (int i = 0; i < 4; ++i) {
        int idx = base + i;
        if (idx < N) { rowptr[idx] = off0; fill[idx] = off0; off0 += v[i]; }
    }
    if (blockIdx.x == 0 && t == 0) rowptr[N] = E;
}

__global__ __launch_bounds__(256) void csr_fill_kernel(
    const int* __restrict__ src, const int* __restrict__ dst,
    const float* __restrict__ ew, int* __restrict__ fill,
    int2* __restrict__ csr, int E)
{
    int e = blockIdx.x * 256 + threadIdx.x;
    if (e >= E) return;
    int d = dst[e];
    int pos = atomicAdd(&fill[d], 1);
    csr[pos] = make_int2(src[e], __float_as_int(ew[e]));
}

__global__ __launch_bounds__(256) void wsum_csr_kernel(
    const int* __restrict__ rowptr, const int2* __restrict__ csr,
    float* __restrict__ wsum, int N)
{
    int n = blockIdx.x * 256 + threadIdx.x;
    if (n >= N) return;
    int b = rowptr[n], en = rowptr[n + 1];
    float s = 0.f;
    for (int e = b; e < en; ++e) s += __int_as_float(csr[e].y);
    wsum[n] = s;
}

// ===================== weight convert+transpose (fp32 [k][n] -> fp16 [n][k]) ==

__global__ __launch_bounds__(256) void convert_weights_kernel(
    const float* __restrict__ W1, const float* __restrict__ W2,
    const float* __restrict__ W3, _Float16* __restrict__ Wt)
{
    int idx = blockIdx.x * 256 + threadIdx.x;   // over 384*128
    if (idx >= 384 * 128) return;
    int n = idx >> 7, k = idx & 127;
    const float* W = (n < 128) ? W1 : (n < 256) ? W2 : W3;
    int c = n & 127;
    Wt[idx] = (_Float16)W[k * 128 + c];
}

// ===================== input standardization =====================

__global__ __launch_bounds__(256) void colstats_kernel(
    const float* __restrict__ x, int N, float* __restrict__ sums,
    float* __restrict__ sumsq)
{
    __shared__ float ls[256], lss[256];
    int t = threadIdx.x;
    int f = t & 127;
    int rstart = blockIdx.x * 2 + (t >> 7);
    int stride = gridDim.x * 2;
    float s = 0.f, ss = 0.f;
    for (int r = rstart; r < N; r += stride) {
        float v = x[(size_t)r * 128 + f];
        s += v; ss += v * v;
    }
    ls[t] = s; lss[t] = ss;
    __syncthreads();
    if (t < 128) {
        atomicAdd(&sums[t], ls[t] + ls[t + 128]);
        atomicAdd(&sumsq[t], lss[t] + lss[t + 128]);
    }
}

__global__ void finalize_stats_kernel(const float* __restrict__ sums,
                                      const float* __restrict__ sumsq, int N,
                                      float* __restrict__ mean,
                                      float* __restrict__ rstd)
{
    int f = threadIdx.x;  // 128 threads
    float s = sums[f], ss = sumsq[f];
    float m = s / (float)N;
    float var = (ss - s * s / (float)N) / (float)(N - 1);  // ddof=1
    var = fmaxf(var, 0.f);
    mean[f] = m;
    rstd[f] = 1.f / (sqrtf(var) + 1e-6f);
}

__global__ __launch_bounds__(256) void standardize_kernel(
    const float* __restrict__ x, const float* __restrict__ mean,
    const float* __restrict__ rstd, _Float16* __restrict__ out, long long total)
{
    long long i = (long long)blockIdx.x * blockDim.x + threadIdx.x;
    if (i >= total) return;
    int f = (int)(i & 127);
    out[i] = (_Float16)((x[i] - mean[f]) * rstd[f]);
}

// ===================== MFMA fused GEMM =====================
// A = h (fp16, [N,128]) ; B = Wt (fp16, [384,128] n-major, = [W1|W2|W3]^T)
// out_a (fp16) = h@W1+b1 ; out_d (fp32) = h@W3+b3 - wsum*(h@W2)
// block = 256 thr = 4 waves; wave w computes rows [blk*64+16w, +16), all 384 cols.

__global__ __launch_bounds__(256) void gemm_mfma_kernel(
    const _Float16* __restrict__ h, int N,
    const _Float16* __restrict__ Wt,
    const float* __restrict__ b1,
    const float* __restrict__ b3,
    const float* __restrict__ wsum,
    _Float16* __restrict__ out_a, float* __restrict__ out_d)
{
    int t = threadIdx.x;
    int wave = t >> 6;
    int lane = t & 63;
    int quad = lane >> 4;     // 0..3
    int c16  = lane & 15;     // 0..15
    int rowBase = blockIdx.x * 64 + wave * 16;

    // ---- load A fragments (4 k-steps), lane holds A[m=c16][k=quad*8..+7]
    const f16x8* hv = (const f16x8*)h;   // row stride 16 (128 halves / 8)
    int arow = rowBase + c16;
    if (arow >= N) arow = N - 1;         // clamp; stores are guarded
    f16x8 afrag[4];
    #pragma unroll
    for (int s = 0; s < 4; ++s)
        afrag[s] = hv[(size_t)arow * 16 + s * 4 + quad];

    // ---- 24 n-tiles of 16 cols; acc[nt] = 16x16 tile (4 f32/lane)
    const f16x8* wv = (const f16x8*)Wt;  // row (n) stride 16
    f32x4 acc[24];
    #pragma unroll
    for (int nt = 0; nt < 24; ++nt) acc[nt] = (f32x4){0.f, 0.f, 0.f, 0.f};

    #pragma unroll
    for (int nt = 0; nt < 24; ++nt) {
        int nrow = nt * 16 + c16;        // B fragment: lane holds B[k][n=c16']
        #pragma unroll
        for (int s = 0; s < 4; ++s) {
            f16x8 bfrag = wv[(size_t)nrow * 16 + s * 4 + quad];
            acc[nt] = __builtin_amdgcn_mfma_f32_16x16x32_f16(afrag[s], bfrag, acc[nt], 0, 0, 0);
        }
    }

    // ---- epilogue: C/D layout col=lane&15, row=quad*4+reg
    #pragma unroll
    for (int reg = 0; reg < 4; ++reg) {
        int grow = rowBase + quad * 4 + reg;
        if (grow >= N) continue;
        float ws = wsum[grow];
        #pragma unroll
        for (int nt = 0; nt < 8; ++nt) {
            int col = nt * 16 + c16;
            float a = acc[nt][reg] + b1[col];
            out_a[(size_t)grow * 128 + col] = (_Float16)a;
            float d = acc[nt + 16][reg] + b3[col] - ws * acc[nt + 8][reg];
            out_d[(size_t)grow * 128 + col] = d;
        }
    }
}

// ===================== fused gather + LN + leaky (fp16 a, fp16 h out) =======

__global__ __launch_bounds__(256) void aggregate_ln_kernel(
    const int* __restrict__ rowptr, const int2* __restrict__ csr,
    const _Float16* __restrict__ a, const float* __restrict__ d,
    const float* __restrict__ g, const float* __restrict__ beta,
    _Float16* __restrict__ out, int N)
{
    int wave = threadIdx.x >> 6;
    int lane = threadIdx.x & 63;
    int node = blockIdx.x * 4 + wave;
    if (node >= N) return;
    int b = rowptr[node], en = rowptr[node + 1];
    float acc0 = 0.f, acc1 = 0.f;
    const f16x2* av = (const f16x2*)a;   // row stride 64
    int e = b;
    for (; e + 1 < en; e += 2) {
        int2 p0 = csr[e], p1 = csr[e + 1];
        f16x2 v0 = av[(size_t)p0.x * 64 + lane];
        f16x2 v1 = av[(size_t)p1.x * 64 + lane];
        float w0 = __int_as_float(p0.y), w1 = __int_as_float(p1.y);
        acc0 += w0 * (float)v0.x + w1 * (float)v1.x;
        acc1 += w0 * (float)v0.y + w1 * (float)v1.y;
    }
    if (e < en) {
        int2 p = csr[e];
        f16x2 v = av[(size_t)p.x * 64 + lane];
        float w = __int_as_float(p.y);
        acc0 += w * (float)v.x;
        acc1 += w * (float)v.y;
    }
    float2 dv = ((const float2*)d)[(size_t)node * 64 + lane];
    float v0 = acc0 + dv.x, v1 = acc1 + dv.y;
    float s  = wave_reduce_sum(v0 + v1);
    float ss = wave_reduce_sum(v0 * v0 + v1 * v1);
    float mean = s * (1.f / 128.f);
    float var = ss * (1.f / 128.f) - mean * mean;
    float rstd = rsqrtf(var + 1e-5f);
    float2 gv = ((const float2*)g)[lane];
    float2 bv = ((const float2*)beta)[lane];
    float o0 = (v0 - mean) * rstd * gv.x + bv.x;
    float o1 = (v1 - mean) * rstd * gv.y + bv.y;
    o0 = o0 >= 0.f ? o0 : 0.1f * o0;
    o1 = o1 >= 0.f ? o1 : 0.1f * o1;
    f16x2 ov; ov.x = (_Float16)o0; ov.y = (_Float16)o1;
    ((f16x2*)out)[(size_t)node * 64 + lane] = ov;
}

// ===================== output layer (D_OUT=1) =====================

__global__ __launch_bounds__(256) void out_gemv_kernel(
    const _Float16* __restrict__ h, int N,
    const float* __restrict__ W1, const float* __restrict__ b1,
    const float* __restrict__ W2,
    const float* __restrict__ W3, const float* __restrict__ b3,
    const float* __restrict__ wsum,
    float* __restrict__ a1, float* __restrict__ dpart)
{
    int wave = threadIdx.x >> 6;
    int lane = threadIdx.x & 63;
    int node = blockIdx.x * 4 + wave;
    if (node >= N) return;
    const _Float16* row = h + (size_t)node * 128;
    float h0 = (float)row[lane], h1 = (float)row[lane + 64];
    float s1 = wave_reduce_sum(h0 * W1[lane] + h1 * W1[lane + 64]);
    float s2 = wave_reduce_sum(h0 * W2[lane] + h1 * W2[lane + 64]);
    float s3 = wave_reduce_sum(h0 * W3[lane] + h1 * W3[lane + 64]);
    if (lane == 0) {
        a1[node] = s1 + b1[0];
        dpart[node] = s3 + b3[0] - wsum[node] * s2;
    }
}

__global__ __launch_bounds__(256) void gather_out_kernel(
    const int* __restrict__ rowptr, const int2* __restrict__ csr,
    const float* __restrict__ a1, const float* __restrict__ dpart,
    float* __restrict__ out, int N)
{
    int n = blockIdx.x * 256 + threadIdx.x;
    if (n >= N) return;
    int b = rowptr[n], en = rowptr[n + 1];
    float s = dpart[n];
    for (int e = b; e < en; ++e) {
        int2 p = csr[e];
        s += __int_as_float(p.y) * a1[p.x];
    }
    out[n] = 1.f / (1.f + expf(-s));
}

// ---------------------------------------------------------------------------
extern "C" void kernel_launch(void* const* d_in, const int* in_sizes, int n_in,
                              void* d_out, int out_size, void* d_ws, size_t ws_size,
                              hipStream_t stream)
{
    const float* x     = (const float*)d_in[0];
    const float* ew    = (const float*)d_in[1];
    const float* W1_in = (const float*)d_in[2];
    const float* b1_in = (const float*)d_in[3];
    const float* W2_in = (const float*)d_in[4];
    const float* W3_in = (const float*)d_in[5];
    const float* b3_in = (const float*)d_in[6];
    const float* W1_h  = (const float*)d_in[7];
    const float* b1_h  = (const float*)d_in[8];
    const float* W2_h  = (const float*)d_in[9];
    const float* W3_h  = (const float*)d_in[10];
    const float* b3_h  = (const float*)d_in[11];
    const float* W1_o  = (const float*)d_in[12];
    const float* b1_o  = (const float*)d_in[13];
    const float* W2_o  = (const float*)d_in[14];
    const float* W3_o  = (const float*)d_in[15];
    const float* b3_o  = (const float*)d_in[16];
    const float* g1    = (const float*)d_in[17];
    const float* beta1 = (const float*)d_in[18];
    const float* g2    = (const float*)d_in[19];
    const float* beta2 = (const float*)d_in[20];
    const int*   eidx  = (const int*)d_in[21];

    const int N = in_sizes[0] / 128;
    const int E = in_sizes[1];
    const int* srcp = eidx;
    const int* dstp = eidx + E;

    // ---- workspace carve-out (256B-aligned chunks) ----
    size_t off = 0;
    auto carve = [&](size_t nbytes) -> void* {
        void* p = (char*)d_ws + off;
        off += (nbytes + 255) & ~(size_t)255;
        return p;
    };
    _Float16* buf_h  = (_Float16*)carve((size_t)N * 128 * 2);
    _Float16* buf_a  = (_Float16*)carve((size_t)N * 128 * 2);
    float*    buf_d  = (float*)   carve((size_t)N * 128 * 4);
    int2*     csr    = (int2*)    carve((size_t)E * 8);
    _Float16* Wt_in  = (_Float16*)carve(384 * 128 * 2);
    _Float16* Wt_h   = (_Float16*)carve(384 * 128 * 2);
    int*      deg    = (int*)     carve((size_t)N * 4);
    int*      rowptr = (int*)     carve((size_t)(N + 1) * 4);
    int*      fill   = (int*)     carve((size_t)N * 4);
    int*      partial= (int*)     carve(256 * 4);
    float*    stats  = (float*)   carve(256 * 4);
    float*    meanp  = (float*)   carve(128 * 4);
    float*    rstdp  = (float*)   carve(128 * 4);
    float*    wsum   = (float*)   carve((size_t)N * 4);
    float*    a1     = (float*)   carve((size_t)N * 4);
    float*    dpart  = (float*)   carve((size_t)N * 4);

    const long long totNF = (long long)N * 128;
    const int nodeWaveBlocks = (N + 3) / 4;
    const int eBlocks = (E + 255) / 256;
    const int nBlocks = (N + 255) / 256;
    const int nb = (N + 1023) / 1024;
    const int wBlocks = (384 * 128 + 255) / 256;

    hipMemsetAsync(deg, 0, (size_t)N * 4, stream);
    hipMemsetAsync(stats, 0, 256 * 4, stream);

    // ---- CSR build + weight conversion ----
    hist_kernel<<<eBlocks, 256, 0, stream>>>(dstp, deg, E);
    scan_pass1<<<nb, 256, 0, stream>>>(deg, N, partial);
    scan_pass2<<<1, 256, 0, stream>>>(partial, nb);
    scan_pass3<<<nb, 256, 0, stream>>>(deg, N, partial, rowptr, fill, E);
    csr_fill_kernel<<<eBlocks, 256, 0, stream>>>(srcp, dstp, ew, fill, csr, E);
    wsum_csr_kernel<<<nBlocks, 256, 0, stream>>>(rowptr, csr, wsum, N);
    convert_weights_kernel<<<wBlocks, 256, 0, stream>>>(W1_in, W2_in, W3_in, Wt_in);
    convert_weights_kernel<<<wBlocks, 256, 0, stream>>>(W1_h, W2_h, W3_h, Wt_h);

    // ---- input standardization (writes fp16 h) ----
    colstats_kernel<<<256, 256, 0, stream>>>(x, N, stats, stats + 128);
    finalize_stats_kernel<<<1, 128, 0, stream>>>(stats, stats + 128, N, meanp, rstdp);
    standardize_kernel<<<(int)((totNF + 255) / 256), 256, 0, stream>>>(x, meanp, rstdp, buf_h, totNF);

    const int gemmBlocks = (N + 63) / 64;

    // ---- layer 1 ----
    gemm_mfma_kernel<<<gemmBlocks, 256, 0, stream>>>(buf_h, N, Wt_in, b1_in, b3_in, wsum, buf_a, buf_d);
    aggregate_ln_kernel<<<nodeWaveBlocks, 256, 0, stream>>>(rowptr, csr, buf_a, buf_d, g1, beta1, buf_h, N);

    // ---- layers 2..3 ----
    for (int l = 0; l < 2; ++l) {
        gemm_mfma_kernel<<<gemmBlocks, 256, 0, stream>>>(buf_h, N, Wt_h, b1_h, b3_h, wsum, buf_a, buf_d);
        aggregate_ln_kernel<<<nodeWaveBlocks, 256, 0, stream>>>(rowptr, csr, buf_a, buf_d, g2, beta2, buf_h, N);
    }

    // ---- output layer ----
    out_gemv_kernel<<<nodeWaveBlocks, 256, 0, stream>>>(buf_h, N, W1_o, b1_o, W2_o, W3_o, b3_o, wsum, a1, dpart);
    gather_out_kernel<<<nBlocks, 256, 0, stream>>>(rowptr, csr, a1, dpart, (float*)d_out, N);
}

// Round 4
// 537.514 us; speedup vs baseline: 2.5041x; 1.0206x over previous
//
#include <hip/hip_runtime.h>
#include <hip/hip_bf16.h>
#include <math.h>

// ---------------------------------------------------------------------------
// GNN_72103910966081: 4-layer LEConv GNN, N=50000, E=600000, D=128.
// Round 3: coalesced GEMM epilogue via LDS staging (dwordx4 stores instead of
// 64 scalar stores/lane), fp16 d buffer (halves GEMM write + aggregate read).
// ---------------------------------------------------------------------------

typedef _Float16 f16x8 __attribute__((ext_vector_type(8)));
typedef _Float16 f16x2 __attribute__((ext_vector_type(2)));
typedef float f32x4 __attribute__((ext_vector_type(4)));

__device__ inline float wave_reduce_sum(float v) {
    #pragma unroll
    for (int off = 32; off > 0; off >>= 1)
        v += __shfl_xor(v, off, 64);
    return v;
}

// ===================== CSR build =====================

__global__ __launch_bounds__(256) void hist_kernel(
    const int* __restrict__ dst, int* __restrict__ deg, int E)
{
    int e = blockIdx.x * 256 + threadIdx.x;
    if (e < E) atomicAdd(&deg[dst[e]], 1);
}

__global__ __launch_bounds__(256) void scan_pass1(
    const int* __restrict__ deg, int N, int* __restrict__ partial)
{
    __shared__ int sh[256];
    int t = threadIdx.x;
    int base = blockIdx.x * 1024 + t * 4;
    int s = 0;
    #pragma unroll
    for (int i = 0; i < 4; ++i) { int idx = base + i; if (idx < N) s += deg[idx]; }
    sh[t] = s; __syncthreads();
    for (int off = 128; off > 0; off >>= 1) {
        if (t < off) sh[t] += sh[t + off];
        __syncthreads();
    }
    if (t == 0) partial[blockIdx.x] = sh[0];
}

__global__ __launch_bounds__(256) void scan_pass2(int* __restrict__ partial, int nb)
{
    __shared__ int sh[256];
    int t = threadIdx.x;
    sh[t] = (t < nb) ? partial[t] : 0;
    __syncthreads();
    for (int off = 1; off < 256; off <<= 1) {
        int x = sh[t];
        if (t >= off) x += sh[t - off];
        __syncthreads();
        sh[t] = x;
        __syncthreads();
    }
    if (t < nb) partial[t] = (t > 0) ? sh[t - 1] : 0;   // exclusive
}

__global__ __launch_bounds__(256) void scan_pass3(
    const int* __restrict__ deg, int N, const int* __restrict__ partial,
    int* __restrict__ rowptr, int* __restrict__ fill, int E)
{
    __shared__ int sh[256];
    int t = threadIdx.x;
    int base = blockIdx.x * 1024 + t * 4;
    int v[4]; int s = 0;
    #pragma unroll
    for (int i = 0; i < 4; ++i) { int idx = base + i; v[i] = (idx < N) ? deg[idx] : 0; s += v[i]; }
    sh[t] = s; __syncthreads();
    for (int off = 1; off < 256; off <<= 1) {
        int x = sh[t];
        if (t >= off) x += sh[t - off];
        __syncthreads();
        sh[t] = x;
        __syncthreads();
    }
    int off0 = partial[blockIdx.x] + ((t > 0) ? sh[t - 1] : 0);
    #pragma unroll
    for (int i = 0; i < 4; ++i) {
        int idx = base + i;
        if (idx < N) { rowptr[idx] = off0; fill[idx] = off0; off0 += v[i]; }
    }
    if (blockIdx.x == 0 && t == 0) rowptr[N] = E;
}

__global__ __launch_bounds__(256) void csr_fill_kernel(
    const int* __restrict__ src, const int* __restrict__ dst,
    const float* __restrict__ ew, int* __restrict__ fill,
    int2* __restrict__ csr, int E)
{
    int e = blockIdx.x * 256 + threadIdx.x;
    if (e >= E) return;
    int d = dst[e];
    int pos = atomicAdd(&fill[d], 1);
    csr[pos] = make_int2(src[e], __float_as_int(ew[e]));
}

__global__ __launch_bounds__(256) void wsum_csr_kernel(
    const int* __restrict__ rowptr, const int2* __restrict__ csr,
    float* __restrict__ wsum, int N)
{
    int n = blockIdx.x * 256 + threadIdx.x;
    if (n >= N) return;
    int b = rowptr[n], en = rowptr[n + 1];
    float s = 0.f;
    for (int e = b; e < en; ++e) s += __int_as_float(csr[e].y);
    wsum[n] = s;
}

// ===================== weight convert+transpose (fp32 [k][n] -> fp16 [n][k]) ==

__global__ __launch_bounds__(256) void convert_weights_kernel(
    const float* __restrict__ W1, const float* __restrict__ W2,
    const float* __restrict__ W3, _Float16* __restrict__ Wt)
{
    int idx = blockIdx.x * 256 + threadIdx.x;   // over 384*128
    if (idx >= 384 * 128) return;
    int n = idx >> 7, k = idx & 127;
    const float* W = (n < 128) ? W1 : (n < 256) ? W2 : W3;
    int c = n & 127;
    Wt[idx] = (_Float16)W[k * 128 + c];
}

// ===================== input standardization =====================

__global__ __launch_bounds__(256) void colstats_kernel(
    const float* __restrict__ x, int N, float* __restrict__ sums,
    float* __restrict__ sumsq)
{
    __shared__ float ls[256], lss[256];
    int t = threadIdx.x;
    int f = t & 127;
    int rstart = blockIdx.x * 2 + (t >> 7);
    int stride = gridDim.x * 2;
    float s = 0.f, ss = 0.f;
    for (int r = rstart; r < N; r += stride) {
        float v = x[(size_t)r * 128 + f];
        s += v; ss += v * v;
    }
    ls[t] = s; lss[t] = ss;
    __syncthreads();
    if (t < 128) {
        atomicAdd(&sums[t], ls[t] + ls[t + 128]);
        atomicAdd(&sumsq[t], lss[t] + lss[t + 128]);
    }
}

__global__ void finalize_stats_kernel(const float* __restrict__ sums,
                                      const float* __restrict__ sumsq, int N,
                                      float* __restrict__ mean,
                                      float* __restrict__ rstd)
{
    int f = threadIdx.x;  // 128 threads
    float s = sums[f], ss = sumsq[f];
    float m = s / (float)N;
    float var = (ss - s * s / (float)N) / (float)(N - 1);  // ddof=1
    var = fmaxf(var, 0.f);
    mean[f] = m;
    rstd[f] = 1.f / (sqrtf(var) + 1e-6f);
}

__global__ __launch_bounds__(256) void standardize_kernel(
    const float* __restrict__ x, const float* __restrict__ mean,
    const float* __restrict__ rstd, _Float16* __restrict__ out, long long total)
{
    long long i = (long long)blockIdx.x * blockDim.x + threadIdx.x;
    if (i >= total) return;
    int f = (int)(i & 127);
    out[i] = (_Float16)((x[i] - mean[f]) * rstd[f]);
}

// ===================== MFMA fused GEMM =====================
// A = h (fp16, [N,128]) ; B = Wt (fp16, [384,128] n-major, = [W1|W2|W3]^T)
// out_a (fp16) = h@W1+b1 ; out_d (fp16) = h@W3+b3 - wsum*(h@W2)
// block = 256 thr = 4 waves; wave w computes rows [blk*64+16w, +16), all 384 cols.
// Epilogue stages C tiles in LDS, stores coalesced dwordx4.

#define LDS_STRIDE 136   // 128 + 8 fp16 pad: keeps 16B alignment, breaks bank pattern

__global__ __launch_bounds__(256) void gemm_mfma_kernel(
    const _Float16* __restrict__ h, int N,
    const _Float16* __restrict__ Wt,
    const float* __restrict__ b1,
    const float* __restrict__ b3,
    const float* __restrict__ wsum,
    _Float16* __restrict__ out_a, _Float16* __restrict__ out_d)
{
    __shared__ _Float16 lds_a[64 * LDS_STRIDE];
    __shared__ _Float16 lds_d[64 * LDS_STRIDE];

    int t = threadIdx.x;
    int wave = t >> 6;
    int lane = t & 63;
    int quad = lane >> 4;     // 0..3
    int c16  = lane & 15;     // 0..15
    int blockRow0 = blockIdx.x * 64;
    int rowBase = blockRow0 + wave * 16;

    // ---- load A fragments (4 k-steps), lane holds A[m=c16][k=quad*8..+7]
    const f16x8* hv = (const f16x8*)h;   // row stride 16 (128 halves / 8)
    int arow = rowBase + c16;
    if (arow >= N) arow = N - 1;         // clamp; stores are guarded
    f16x8 afrag[4];
    #pragma unroll
    for (int s = 0; s < 4; ++s)
        afrag[s] = hv[(size_t)arow * 16 + s * 4 + quad];

    // ---- 24 n-tiles of 16 cols; acc[nt] = 16x16 tile (4 f32/lane)
    const f16x8* wv = (const f16x8*)Wt;  // row (n) stride 16
    f32x4 acc[24];
    #pragma unroll
    for (int nt = 0; nt < 24; ++nt) acc[nt] = (f32x4){0.f, 0.f, 0.f, 0.f};

    #pragma unroll
    for (int nt = 0; nt < 24; ++nt) {
        int nrow = nt * 16 + c16;        // B fragment: lane holds B[k][n=c16']
        #pragma unroll
        for (int s = 0; s < 4; ++s) {
            f16x8 bfrag = wv[(size_t)nrow * 16 + s * 4 + quad];
            acc[nt] = __builtin_amdgcn_mfma_f32_16x16x32_f16(afrag[s], bfrag, acc[nt], 0, 0, 0);
        }
    }

    // ---- epilogue: C/D layout col=lane&15, row=quad*4+reg -> LDS (fp16)
    float bb1[8], bb3[8];
    #pragma unroll
    for (int nt = 0; nt < 8; ++nt) {
        int col = nt * 16 + c16;
        bb1[nt] = b1[col];
        bb3[nt] = b3[col];
    }
    float wsv[4];
    #pragma unroll
    for (int reg = 0; reg < 4; ++reg) {
        int grow = rowBase + quad * 4 + reg;
        wsv[reg] = wsum[(grow < N) ? grow : (N - 1)];
    }

    #pragma unroll
    for (int nt = 0; nt < 8; ++nt) {
        int col = nt * 16 + c16;
        #pragma unroll
        for (int reg = 0; reg < 4; ++reg) {
            int lrow = wave * 16 + quad * 4 + reg;
            lds_a[lrow * LDS_STRIDE + col] = (_Float16)(acc[nt][reg] + bb1[nt]);
            lds_d[lrow * LDS_STRIDE + col] =
                (_Float16)(acc[nt + 16][reg] + bb3[nt] - wsv[reg] * acc[nt + 8][reg]);
        }
    }
    __syncthreads();

    // ---- coalesced stores: 64 rows x 128 fp16 = 1024 chunks of 16B each buf
    f16x8* oa = (f16x8*)out_a;   // row stride 16 chunks
    f16x8* od = (f16x8*)out_d;
    #pragma unroll
    for (int i = 0; i < 4; ++i) {
        int idx = i * 256 + t;       // 0..1023
        int row = idx >> 4;          // 0..63
        int c8  = idx & 15;          // 16B chunk within row
        int grow = blockRow0 + row;
        if (grow < N) {
            f16x8 va = *(const f16x8*)&lds_a[row * LDS_STRIDE + c8 * 8];
            oa[(size_t)grow * 16 + c8] = va;
            f16x8 vd = *(const f16x8*)&lds_d[row * LDS_STRIDE + c8 * 8];
            od[(size_t)grow * 16 + c8] = vd;
        }
    }
}

// ===================== fused gather + LN + leaky (fp16 a/d, fp16 h out) =====

__global__ __launch_bounds__(256) void aggregate_ln_kernel(
    const int* __restrict__ rowptr, const int2* __restrict__ csr,
    const _Float16* __restrict__ a, const _Float16* __restrict__ d,
    const float* __restrict__ g, const float* __restrict__ beta,
    _Float16* __restrict__ out, int N)
{
    int wave = threadIdx.x >> 6;
    int lane = threadIdx.x & 63;
    int node = blockIdx.x * 4 + wave;
    if (node >= N) return;
    int b = rowptr[node], en = rowptr[node + 1];
    float acc0 = 0.f, acc1 = 0.f;
    const f16x2* av = (const f16x2*)a;   // row stride 64
    int e = b;
    for (; e + 1 < en; e += 2) {
        int2 p0 = csr[e], p1 = csr[e + 1];
        f16x2 v0 = av[(size_t)p0.x * 64 + lane];
        f16x2 v1 = av[(size_t)p1.x * 64 + lane];
        float w0 = __int_as_float(p0.y), w1 = __int_as_float(p1.y);
        acc0 += w0 * (float)v0.x + w1 * (float)v1.x;
        acc1 += w0 * (float)v0.y + w1 * (float)v1.y;
    }
    if (e < en) {
        int2 p = csr[e];
        f16x2 v = av[(size_t)p.x * 64 + lane];
        float w = __int_as_float(p.y);
        acc0 += w * (float)v.x;
        acc1 += w * (float)v.y;
    }
    f16x2 dv = ((const f16x2*)d)[(size_t)node * 64 + lane];
    float v0 = acc0 + (float)dv.x, v1 = acc1 + (float)dv.y;
    float s  = wave_reduce_sum(v0 + v1);
    float ss = wave_reduce_sum(v0 * v0 + v1 * v1);
    float mean = s * (1.f / 128.f);
    float var = ss * (1.f / 128.f) - mean * mean;
    float rstd = rsqrtf(var + 1e-5f);
    float2 gv = ((const float2*)g)[lane];
    float2 bv = ((const float2*)beta)[lane];
    float o0 = (v0 - mean) * rstd * gv.x + bv.x;
    float o1 = (v1 - mean) * rstd * gv.y + bv.y;
    o0 = o0 >= 0.f ? o0 : 0.1f * o0;
    o1 = o1 >= 0.f ? o1 : 0.1f * o1;
    f16x2 ov; ov.x = (_Float16)o0; ov.y = (_Float16)o1;
    ((f16x2*)out)[(size_t)node * 64 + lane] = ov;
}

// ===================== output layer (D_OUT=1) =====================

__global__ __launch_bounds__(256) void out_gemv_kernel(
    const _Float16* __restrict__ h, int N,
    const float* __restrict__ W1, const float* __restrict__ b1,
    const float* __restrict__ W2,
    const float* __restrict__ W3, const float* __restrict__ b3,
    const float* __restrict__ wsum,
    float* __restrict__ a1, float* __restrict__ dpart)
{
    int wave = threadIdx.x >> 6;
    int lane = threadIdx.x & 63;
    int node = blockIdx.x * 4 + wave;
    if (node >= N) return;
    const _Float16* row = h + (size_t)node * 128;
    float h0 = (float)row[lane], h1 = (float)row[lane + 64];
    float s1 = wave_reduce_sum(h0 * W1[lane] + h1 * W1[lane + 64]);
    float s2 = wave_reduce_sum(h0 * W2[lane] + h1 * W2[lane + 64]);
    float s3 = wave_reduce_sum(h0 * W3[lane] + h1 * W3[lane + 64]);
    if (lane == 0) {
        a1[node] = s1 + b1[0];
        dpart[node] = s3 + b3[0] - wsum[node] * s2;
    }
}

__global__ __launch_bounds__(256) void gather_out_kernel(
    const int* __restrict__ rowptr, const int2* __restrict__ csr,
    const float* __restrict__ a1, const float* __restrict__ dpart,
    float* __restrict__ out, int N)
{
    int n = blockIdx.x * 256 + threadIdx.x;
    if (n >= N) return;
    int b = rowptr[n], en = rowptr[n + 1];
    float s = dpart[n];
    for (int e = b; e < en; ++e) {
        int2 p = csr[e];
        s += __int_as_float(p.y) * a1[p.x];
    }
    out[n] = 1.f / (1.f + expf(-s));
}

// ---------------------------------------------------------------------------
extern "C" void kernel_launch(void* const* d_in, const int* in_sizes, int n_in,
                              void* d_out, int out_size, void* d_ws, size_t ws_size,
                              hipStream_t stream)
{
    const float* x     = (const float*)d_in[0];
    const float* ew    = (const float*)d_in[1];
    const float* W1_in = (const float*)d_in[2];
    const float* b1_in = (const float*)d_in[3];
    const float* W2_in = (const float*)d_in[4];
    const float* W3_in = (const float*)d_in[5];
    const float* b3_in = (const float*)d_in[6];
    const float* W1_h  = (const float*)d_in[7];
    const float* b1_h  = (const float*)d_in[8];
    const float* W2_h  = (const float*)d_in[9];
    const float* W3_h  = (const float*)d_in[10];
    const float* b3_h  = (const float*)d_in[11];
    const float* W1_o  = (const float*)d_in[12];
    const float* b1_o  = (const float*)d_in[13];
    const float* W2_o  = (const float*)d_in[14];
    const float* W3_o  = (const float*)d_in[15];
    const float* b3_o  = (const float*)d_in[16];
    const float* g1    = (const float*)d_in[17];
    const float* beta1 = (const float*)d_in[18];
    const float* g2    = (const float*)d_in[19];
    const float* beta2 = (const float*)d_in[20];
    const int*   eidx  = (const int*)d_in[21];

    const int N = in_sizes[0] / 128;
    const int E = in_sizes[1];
    const int* srcp = eidx;
    const int* dstp = eidx + E;

    // ---- workspace carve-out (256B-aligned chunks) ----
    size_t off = 0;
    auto carve = [&](size_t nbytes) -> void* {
        void* p = (char*)d_ws + off;
        off += (nbytes + 255) & ~(size_t)255;
        return p;
    };
    _Float16* buf_h  = (_Float16*)carve((size_t)N * 128 * 2);
    _Float16* buf_a  = (_Float16*)carve((size_t)N * 128 * 2);
    _Float16* buf_d  = (_Float16*)carve((size_t)N * 128 * 2);
    int2*     csr    = (int2*)    carve((size_t)E * 8);
    _Float16* Wt_in  = (_Float16*)carve(384 * 128 * 2);
    _Float16* Wt_h   = (_Float16*)carve(384 * 128 * 2);
    int*      deg    = (int*)     carve((size_t)N * 4);
    int*      rowptr = (int*)     carve((size_t)(N + 1) * 4);
    int*      fill   = (int*)     carve((size_t)N * 4);
    int*      partial= (int*)     carve(256 * 4);
    float*    stats  = (float*)   carve(256 * 4);
    float*    meanp  = (float*)   carve(128 * 4);
    float*    rstdp  = (float*)   carve(128 * 4);
    float*    wsum   = (float*)   carve((size_t)N * 4);
    float*    a1     = (float*)   carve((size_t)N * 4);
    float*    dpart  = (float*)   carve((size_t)N * 4);

    const long long totNF = (long long)N * 128;
    const int nodeWaveBlocks = (N + 3) / 4;
    const int eBlocks = (E + 255) / 256;
    const int nBlocks = (N + 255) / 256;
    const int nb = (N + 1023) / 1024;
    const int wBlocks = (384 * 128 + 255) / 256;

    hipMemsetAsync(deg, 0, (size_t)N * 4, stream);
    hipMemsetAsync(stats, 0, 256 * 4, stream);

    // ---- CSR build + weight conversion ----
    hist_kernel<<<eBlocks, 256, 0, stream>>>(dstp, deg, E);
    scan_pass1<<<nb, 256, 0, stream>>>(deg, N, partial);
    scan_pass2<<<1, 256, 0, stream>>>(partial, nb);
    scan_pass3<<<nb, 256, 0, stream>>>(deg, N, partial, rowptr, fill, E);
    csr_fill_kernel<<<eBlocks, 256, 0, stream>>>(srcp, dstp, ew, fill, csr, E);
    wsum_csr_kernel<<<nBlocks, 256, 0, stream>>>(rowptr, csr, wsum, N);
    convert_weights_kernel<<<wBlocks, 256, 0, stream>>>(W1_in, W2_in, W3_in, Wt_in);
    convert_weights_kernel<<<wBlocks, 256, 0, stream>>>(W1_h, W2_h, W3_h, Wt_h);

    // ---- input standardization (writes fp16 h) ----
    colstats_kernel<<<256, 256, 0, stream>>>(x, N, stats, stats + 128);
    finalize_stats_kernel<<<1, 128, 0, stream>>>(stats, stats + 128, N, meanp, rstdp);
    standardize_kernel<<<(int)((totNF + 255) / 256), 256, 0, stream>>>(x, meanp, rstdp, buf_h, totNF);

    const int gemmBlocks = (N + 63) / 64;

    // ---- layer 1 ----
    gemm_mfma_kernel<<<gemmBlocks, 256, 0, stream>>>(buf_h, N, Wt_in, b1_in, b3_in, wsum, buf_a, buf_d);
    aggregate_ln_kernel<<<nodeWaveBlocks, 256, 0, stream>>>(rowptr, csr, buf_a, buf_d, g1, beta1, buf_h, N);

    // ---- layers 2..3 ----
    for (int l = 0; l < 2; ++l) {
        gemm_mfma_kernel<<<gemmBlocks, 256, 0, stream>>>(buf_h, N, Wt_h, b1_h, b3_h, wsum, buf_a, buf_d);
        aggregate_ln_kernel<<<nodeWaveBlocks, 256, 0, stream>>>(rowptr, csr, buf_a, buf_d, g2, beta2, buf_h, N);
    }

    // ---- output layer ----
    out_gemv_kernel<<<nodeWaveBlocks, 256, 0, stream>>>(buf_h, N, W1_o, b1_o, W2_o, W3_o, b3_o, wsum, a1, dpart);
    gather_out_kernel<<<nBlocks, 256, 0, stream>>>(rowptr, csr, a1, dpart, (float*)d_out, N);
}

// Round 5
// 436.762 us; speedup vs baseline: 3.0817x; 1.2307x over previous
//
#include <hip/hip_runtime.h>
#include <hip/hip_bf16.h>
#include <math.h>

// ---------------------------------------------------------------------------
// GNN_72103910966081: 4-layer LEConv GNN, N=50000, E=600000, D=128.
// Round 5: GEMM restructured — B fragments live in registers (once per block,
// persistent grid-stride over row tiles); A staged via LDS (coalesced);
// inner loop is pure ds_read+MFMA. Kills the exposed global-load latency
// that R3/R4 counters showed (MfmaUtil 3%, VALU 4%, nothing busy).
// ---------------------------------------------------------------------------

typedef _Float16 f16x8 __attribute__((ext_vector_type(8)));
typedef _Float16 f16x2 __attribute__((ext_vector_type(2)));
typedef float f32x4 __attribute__((ext_vector_type(4)));

#define LSTRIDE 136   // halves per LDS row: 128 + 8 (16B-aligned, breaks 2^k banks)

__device__ inline float wave_reduce_sum(float v) {
    #pragma unroll
    for (int off = 32; off > 0; off >>= 1)
        v += __shfl_xor(v, off, 64);
    return v;
}

// ===================== CSR build =====================

__global__ __launch_bounds__(256) void hist_kernel(
    const int* __restrict__ dst, int* __restrict__ deg, int E)
{
    int e = blockIdx.x * 256 + threadIdx.x;
    if (e < E) atomicAdd(&deg[dst[e]], 1);
}

__global__ __launch_bounds__(256) void scan_pass1(
    const int* __restrict__ deg, int N, int* __restrict__ partial)
{
    __shared__ int sh[256];
    int t = threadIdx.x;
    int base = blockIdx.x * 1024 + t * 4;
    int s = 0;
    #pragma unroll
    for (int i = 0; i < 4; ++i) { int idx = base + i; if (idx < N) s += deg[idx]; }
    sh[t] = s; __syncthreads();
    for (int off = 128; off > 0; off >>= 1) {
        if (t < off) sh[t] += sh[t + off];
        __syncthreads();
    }
    if (t == 0) partial[blockIdx.x] = sh[0];
}

__global__ __launch_bounds__(256) void scan_pass2(int* __restrict__ partial, int nb)
{
    __shared__ int sh[256];
    int t = threadIdx.x;
    sh[t] = (t < nb) ? partial[t] : 0;
    __syncthreads();
    for (int off = 1; off < 256; off <<= 1) {
        int x = sh[t];
        if (t >= off) x += sh[t - off];
        __syncthreads();
        sh[t] = x;
        __syncthreads();
    }
    if (t < nb) partial[t] = (t > 0) ? sh[t - 1] : 0;   // exclusive
}

__global__ __launch_bounds__(256) void scan_pass3(
    const int* __restrict__ deg, int N, const int* __restrict__ partial,
    int* __restrict__ rowptr, int* __restrict__ fill, int E)
{
    __shared__ int sh[256];
    int t = threadIdx.x;
    int base = blockIdx.x * 1024 + t * 4;
    int v[4]; int s = 0;
    #pragma unroll
    for (int i = 0; i < 4; ++i) { int idx = base + i; v[i] = (idx < N) ? deg[idx] : 0; s += v[i]; }
    sh[t] = s; __syncthreads();
    for (int off = 1; off < 256; off <<= 1) {
        int x = sh[t];
        if (t >= off) x += sh[t - off];
        __syncthreads();
        sh[t] = x;
        __syncthreads();
    }
    int off0 = partial[blockIdx.x] + ((t > 0) ? sh[t - 1] : 0);
    #pragma unroll
    for (int i = 0; i < 4; ++i) {
        int idx = base + i;
        if (idx < N) { rowptr[idx] = off0; fill[idx] = off0; off0 += v[i]; }
    }
    if (blockIdx.x == 0 && t == 0) rowptr[N] = E;
}

__global__ __launch_bounds__(256) void csr_fill_kernel(
    const int* __restrict__ src, const int* __restrict__ dst,
    const float* __restrict__ ew, int* __restrict__ fill,
    int2* __restrict__ csr, int E)
{
    int e = blockIdx.x * 256 + threadIdx.x;
    if (e >= E) return;
    int d = dst[e];
    int pos = atomicAdd(&fill[d], 1);
    csr[pos] = make_int2(src[e], __float_as_int(ew[e]));
}

__global__ __launch_bounds__(256) void wsum_csr_kernel(
    const int* __restrict__ rowptr, const int2* __restrict__ csr,
    float* __restrict__ wsum, int N)
{
    int n = blockIdx.x * 256 + threadIdx.x;
    if (n >= N) return;
    int b = rowptr[n], en = rowptr[n + 1];
    float s = 0.f;
    for (int e = b; e < en; ++e) s += __int_as_float(csr[e].y);
    wsum[n] = s;
}

// ===================== weight convert+transpose (fp32 [k][n] -> fp16 [n][k]) ==

__global__ __launch_bounds__(256) void convert_weights_kernel(
    const float* __restrict__ W1, const float* __restrict__ W2,
    const float* __restrict__ W3, _Float16* __restrict__ Wt)
{
    int idx = blockIdx.x * 256 + threadIdx.x;   // over 384*128
    if (idx >= 384 * 128) return;
    int n = idx >> 7, k = idx & 127;
    const float* W = (n < 128) ? W1 : (n < 256) ? W2 : W3;
    int c = n & 127;
    Wt[idx] = (_Float16)W[k * 128 + c];
}

// ===================== input standardization =====================

__global__ __launch_bounds__(256) void colstats_kernel(
    const float* __restrict__ x, int N, float* __restrict__ sums,
    float* __restrict__ sumsq)
{
    __shared__ float ls[256], lss[256];
    int t = threadIdx.x;
    int f = t & 127;
    int rstart = blockIdx.x * 2 + (t >> 7);
    int stride = gridDim.x * 2;
    float s = 0.f, ss = 0.f;
    for (int r = rstart; r < N; r += stride) {
        float v = x[(size_t)r * 128 + f];
        s += v; ss += v * v;
    }
    ls[t] = s; lss[t] = ss;
    __syncthreads();
    if (t < 128) {
        atomicAdd(&sums[t], ls[t] + ls[t + 128]);
        atomicAdd(&sumsq[t], lss[t] + lss[t + 128]);
    }
}

__global__ void finalize_stats_kernel(const float* __restrict__ sums,
                                      const float* __restrict__ sumsq, int N,
                                      float* __restrict__ mean,
                                      float* __restrict__ rstd)
{
    int f = threadIdx.x;  // 128 threads
    float s = sums[f], ss = sumsq[f];
    float m = s / (float)N;
    float var = (ss - s * s / (float)N) / (float)(N - 1);  // ddof=1
    var = fmaxf(var, 0.f);
    mean[f] = m;
    rstd[f] = 1.f / (sqrtf(var) + 1e-6f);
}

__global__ __launch_bounds__(256) void standardize_kernel(
    const float* __restrict__ x, const float* __restrict__ mean,
    const float* __restrict__ rstd, _Float16* __restrict__ out, long long total)
{
    long long i = (long long)blockIdx.x * blockDim.x + threadIdx.x;
    if (i >= total) return;
    int f = (int)(i & 127);
    out[i] = (_Float16)((x[i] - mean[f]) * rstd[f]);
}

// ===================== MFMA fused GEMM (persistent, B in registers) ========
// A = h (fp16, [N,128]) ; B = Wt (fp16, [384,128] n-major = [W1|W2|W3]^T)
// out_a (fp16) = h@W1+b1 ; out_d (fp16) = h@W3+b3 - wsum*(h@W2)
// 256 thr = 4 waves. Wave w owns column slice: W1-tiles {2w,2w+1},
// W2-tiles {8+2w,8+2w+1}, W3-tiles {16+2w,16+2w+1} (cols [32w,32w+32) of a,d).
// 24 B-fragments (96 VGPRs) loaded ONCE, held across grid-stride row tiles.

__global__ __launch_bounds__(256, 2) void gemm_mfma_kernel(
    const _Float16* __restrict__ h, int N, int nTiles,
    const _Float16* __restrict__ Wt,
    const float* __restrict__ b1,
    const float* __restrict__ b3,
    const float* __restrict__ wsum,
    _Float16* __restrict__ out_a, _Float16* __restrict__ out_d)
{
    __shared__ _Float16 ldsS[64 * LSTRIDE];   // staged A tile
    __shared__ _Float16 lds_a[64 * LSTRIDE];  // epilogue a
    __shared__ _Float16 lds_d[64 * LSTRIDE];  // epilogue d

    int t = threadIdx.x;
    int wave = t >> 6;
    int lane = t & 63;
    int quad = lane >> 4;     // 0..3
    int c16  = lane & 15;     // 0..15

    // ---- B fragments: 6 n-tiles x 4 k-steps, in registers for the kernel's life
    const f16x8* wv = (const f16x8*)Wt;  // row (n) stride 16 chunks
    int ntl[6] = {2*wave, 2*wave+1, 8+2*wave, 9+2*wave, 16+2*wave, 17+2*wave};
    f16x8 bfrag[6][4];
    #pragma unroll
    for (int j = 0; j < 6; ++j) {
        int nrow = ntl[j] * 16 + c16;
        #pragma unroll
        for (int s = 0; s < 4; ++s)
            bfrag[j][s] = wv[(size_t)nrow * 16 + s * 4 + quad];
    }
    float bb1[2], bb3[2];
    #pragma unroll
    for (int j = 0; j < 2; ++j) {
        int col = (2*wave + j) * 16 + c16;
        bb1[j] = b1[col];
        bb3[j] = b3[col];
    }

    const f16x8* hv = (const f16x8*)h;   // row stride 16 chunks
    f16x8* oa = (f16x8*)out_a;
    f16x8* od = (f16x8*)out_d;

    for (int tile = blockIdx.x; tile < nTiles; tile += gridDim.x) {
        int row0 = tile * 64;

        // ---- stage A tile (64 rows x 256B) into LDS, fully coalesced
        #pragma unroll
        for (int i = 0; i < 4; ++i) {
            int idx = i * 256 + t;        // 0..1023
            int row = idx >> 4;
            int chunk = idx & 15;
            int grow = row0 + row;
            if (grow >= N) grow = N - 1;  // clamp; per-row results discarded later
            *(f16x8*)&ldsS[row * LSTRIDE + chunk * 8] = hv[(size_t)grow * 16 + chunk];
        }
        __syncthreads();

        // ---- 4 row-groups of 16 rows each
        #pragma unroll
        for (int r = 0; r < 4; ++r) {
            f16x8 afrag[4];
            #pragma unroll
            for (int s = 0; s < 4; ++s)
                afrag[s] = *(const f16x8*)&ldsS[(r*16 + c16) * LSTRIDE + (s*4 + quad) * 8];

            f32x4 acc[6];
            #pragma unroll
            for (int j = 0; j < 6; ++j) acc[j] = (f32x4){0.f, 0.f, 0.f, 0.f};
            #pragma unroll
            for (int s = 0; s < 4; ++s) {
                #pragma unroll
                for (int j = 0; j < 6; ++j)
                    acc[j] = __builtin_amdgcn_mfma_f32_16x16x32_f16(afrag[s], bfrag[j][s], acc[j], 0, 0, 0);
            }

            // epilogue -> LDS (C/D layout: col=c16, row=quad*4+reg)
            float wsv[4];
            #pragma unroll
            for (int reg = 0; reg < 4; ++reg) {
                int gr = row0 + r*16 + quad*4 + reg;
                wsv[reg] = wsum[(gr < N) ? gr : (N - 1)];
            }
            #pragma unroll
            for (int j = 0; j < 2; ++j) {
                int col = (2*wave + j) * 16 + c16;
                #pragma unroll
                for (int reg = 0; reg < 4; ++reg) {
                    int lr = r*16 + quad*4 + reg;
                    lds_a[lr * LSTRIDE + col] = (_Float16)(acc[j][reg] + bb1[j]);
                    lds_d[lr * LSTRIDE + col] =
                        (_Float16)(acc[4+j][reg] + bb3[j] - wsv[reg] * acc[2+j][reg]);
                }
            }
        }
        __syncthreads();

        // ---- coalesced stores (64 rows x 16 chunks of 16B, both buffers)
        #pragma unroll
        for (int i = 0; i < 4; ++i) {
            int idx = i * 256 + t;
            int row = idx >> 4;
            int c8  = idx & 15;
            int grow = row0 + row;
            if (grow < N) {
                f16x8 va = *(const f16x8*)&lds_a[row * LSTRIDE + c8 * 8];
                oa[(size_t)grow * 16 + c8] = va;
                f16x8 vd = *(const f16x8*)&lds_d[row * LSTRIDE + c8 * 8];
                od[(size_t)grow * 16 + c8] = vd;
            }
        }
        __syncthreads();   // protect ldsS/lds_* before next iteration's writes
    }
}

// ===================== fused gather + LN + leaky (fp16 a/d, fp16 h out) =====

__global__ __launch_bounds__(256) void aggregate_ln_kernel(
    const int* __restrict__ rowptr, const int2* __restrict__ csr,
    const _Float16* __restrict__ a, const _Float16* __restrict__ d,
    const float* __restrict__ g, const float* __restrict__ beta,
    _Float16* __restrict__ out, int N)
{
    int wave = threadIdx.x >> 6;
    int lane = threadIdx.x & 63;
    int node = blockIdx.x * 4 + wave;
    if (node >= N) return;
    int b = rowptr[node], en = rowptr[node + 1];
    float acc0 = 0.f, acc1 = 0.f;
    const f16x2* av = (const f16x2*)a;   // row stride 64
    int e = b;
    for (; e + 1 < en; e += 2) {
        int2 p0 = csr[e], p1 = csr[e + 1];
        f16x2 v0 = av[(size_t)p0.x * 64 + lane];
        f16x2 v1 = av[(size_t)p1.x * 64 + lane];
        float w0 = __int_as_float(p0.y), w1 = __int_as_float(p1.y);
        acc0 += w0 * (float)v0.x + w1 * (float)v1.x;
        acc1 += w0 * (float)v0.y + w1 * (float)v1.y;
    }
    if (e < en) {
        int2 p = csr[e];
        f16x2 v = av[(size_t)p.x * 64 + lane];
        float w = __int_as_float(p.y);
        acc0 += w * (float)v.x;
        acc1 += w * (float)v.y;
    }
    f16x2 dv = ((const f16x2*)d)[(size_t)node * 64 + lane];
    float v0 = acc0 + (float)dv.x, v1 = acc1 + (float)dv.y;
    float s  = wave_reduce_sum(v0 + v1);
    float ss = wave_reduce_sum(v0 * v0 + v1 * v1);
    float mean = s * (1.f / 128.f);
    float var = ss * (1.f / 128.f) - mean * mean;
    float rstd = rsqrtf(var + 1e-5f);
    float2 gv = ((const float2*)g)[lane];
    float2 bv = ((const float2*)beta)[lane];
    float o0 = (v0 - mean) * rstd * gv.x + bv.x;
    float o1 = (v1 - mean) * rstd * gv.y + bv.y;
    o0 = o0 >= 0.f ? o0 : 0.1f * o0;
    o1 = o1 >= 0.f ? o1 : 0.1f * o1;
    f16x2 ov; ov.x = (_Float16)o0; ov.y = (_Float16)o1;
    ((f16x2*)out)[(size_t)node * 64 + lane] = ov;
}

// ===================== output layer (D_OUT=1) =====================

__global__ __launch_bounds__(256) void out_gemv_kernel(
    const _Float16* __restrict__ h, int N,
    const float* __restrict__ W1, const float* __restrict__ b1,
    const float* __restrict__ W2,
    const float* __restrict__ W3, const float* __restrict__ b3,
    const float* __restrict__ wsum,
    float* __restrict__ a1, float* __restrict__ dpart)
{
    int wave = threadIdx.x >> 6;
    int lane = threadIdx.x & 63;
    int node = blockIdx.x * 4 + wave;
    if (node >= N) return;
    const _Float16* row = h + (size_t)node * 128;
    float h0 = (float)row[lane], h1 = (float)row[lane + 64];
    float s1 = wave_reduce_sum(h0 * W1[lane] + h1 * W1[lane + 64]);
    float s2 = wave_reduce_sum(h0 * W2[lane] + h1 * W2[lane + 64]);
    float s3 = wave_reduce_sum(h0 * W3[lane] + h1 * W3[lane + 64]);
    if (lane == 0) {
        a1[node] = s1 + b1[0];
        dpart[node] = s3 + b3[0] - wsum[node] * s2;
    }
}

__global__ __launch_bounds__(256) void gather_out_kernel(
    const int* __restrict__ rowptr, const int2* __restrict__ csr,
    const float* __restrict__ a1, const float* __restrict__ dpart,
    float* __restrict__ out, int N)
{
    int n = blockIdx.x * 256 + threadIdx.x;
    if (n >= N) return;
    int b = rowptr[n], en = rowptr[n + 1];
    float s = dpart[n];
    for (int e = b; e < en; ++e) {
        int2 p = csr[e];
        s += __int_as_float(p.y) * a1[p.x];
    }
    out[n] = 1.f / (1.f + expf(-s));
}

// ---------------------------------------------------------------------------
extern "C" void kernel_launch(void* const* d_in, const int* in_sizes, int n_in,
                              void* d_out, int out_size, void* d_ws, size_t ws_size,
                              hipStream_t stream)
{
    const float* x     = (const float*)d_in[0];
    const float* ew    = (const float*)d_in[1];
    const float* W1_in = (const float*)d_in[2];
    const float* b1_in = (const float*)d_in[3];
    const float* W2_in = (const float*)d_in[4];
    const float* W3_in = (const float*)d_in[5];
    const float* b3_in = (const float*)d_in[6];
    const float* W1_h  = (const float*)d_in[7];
    const float* b1_h  = (const float*)d_in[8];
    const float* W2_h  = (const float*)d_in[9];
    const float* W3_h  = (const float*)d_in[10];
    const float* b3_h  = (const float*)d_in[11];
    const float* W1_o  = (const float*)d_in[12];
    const float* b1_o  = (const float*)d_in[13];
    const float* W2_o  = (const float*)d_in[14];
    const float* W3_o  = (const float*)d_in[15];
    const float* b3_o  = (const float*)d_in[16];
    const float* g1    = (const float*)d_in[17];
    const float* beta1 = (const float*)d_in[18];
    const float* g2    = (const float*)d_in[19];
    const float* beta2 = (const float*)d_in[20];
    const int*   eidx  = (const int*)d_in[21];

    const int N = in_sizes[0] / 128;
    const int E = in_sizes[1];
    const int* srcp = eidx;
    const int* dstp = eidx + E;

    // ---- workspace carve-out (256B-aligned chunks) ----
    size_t off = 0;
    auto carve = [&](size_t nbytes) -> void* {
        void* p = (char*)d_ws + off;
        off += (nbytes + 255) & ~(size_t)255;
        return p;
    };
    _Float16* buf_h  = (_Float16*)carve((size_t)N * 128 * 2);
    _Float16* buf_a  = (_Float16*)carve((size_t)N * 128 * 2);
    _Float16* buf_d  = (_Float16*)carve((size_t)N * 128 * 2);
    int2*     csr    = (int2*)    carve((size_t)E * 8);
    _Float16* Wt_in  = (_Float16*)carve(384 * 128 * 2);
    _Float16* Wt_h   = (_Float16*)carve(384 * 128 * 2);
    int*      deg    = (int*)     carve((size_t)N * 4);
    int*      rowptr = (int*)     carve((size_t)(N + 1) * 4);
    int*      fill   = (int*)     carve((size_t)N * 4);
    int*      partial= (int*)     carve(256 * 4);
    float*    stats  = (float*)   carve(256 * 4);
    float*    meanp  = (float*)   carve(128 * 4);
    float*    rstdp  = (float*)   carve(128 * 4);
    float*    wsum   = (float*)   carve((size_t)N * 4);
    float*    a1     = (float*)   carve((size_t)N * 4);
    float*    dpart  = (float*)   carve((size_t)N * 4);

    const long long totNF = (long long)N * 128;
    const int nodeWaveBlocks = (N + 3) / 4;
    const int eBlocks = (E + 255) / 256;
    const int nBlocks = (N + 255) / 256;
    const int nb = (N + 1023) / 1024;
    const int wBlocks = (384 * 128 + 255) / 256;

    hipMemsetAsync(deg, 0, (size_t)N * 4, stream);
    hipMemsetAsync(stats, 0, 256 * 4, stream);

    // ---- CSR build + weight conversion ----
    hist_kernel<<<eBlocks, 256, 0, stream>>>(dstp, deg, E);
    scan_pass1<<<nb, 256, 0, stream>>>(deg, N, partial);
    scan_pass2<<<1, 256, 0, stream>>>(partial, nb);
    scan_pass3<<<nb, 256, 0, stream>>>(deg, N, partial, rowptr, fill, E);
    csr_fill_kernel<<<eBlocks, 256, 0, stream>>>(srcp, dstp, ew, fill, csr, E);
    wsum_csr_kernel<<<nBlocks, 256, 0, stream>>>(rowptr, csr, wsum, N);
    convert_weights_kernel<<<wBlocks, 256, 0, stream>>>(W1_in, W2_in, W3_in, Wt_in);
    convert_weights_kernel<<<wBlocks, 256, 0, stream>>>(W1_h, W2_h, W3_h, Wt_h);

    // ---- input standardization (writes fp16 h) ----
    colstats_kernel<<<256, 256, 0, stream>>>(x, N, stats, stats + 128);
    finalize_stats_kernel<<<1, 128, 0, stream>>>(stats, stats + 128, N, meanp, rstdp);
    standardize_kernel<<<(int)((totNF + 255) / 256), 256, 0, stream>>>(x, meanp, rstdp, buf_h, totNF);

    const int nTiles = (N + 63) / 64;
    const int gemmGrid = (nTiles < 512) ? nTiles : 512;

    // ---- layer 1 ----
    gemm_mfma_kernel<<<gemmGrid, 256, 0, stream>>>(buf_h, N, nTiles, Wt_in, b1_in, b3_in, wsum, buf_a, buf_d);
    aggregate_ln_kernel<<<nodeWaveBlocks, 256, 0, stream>>>(rowptr, csr, buf_a, buf_d, g1, beta1, buf_h, N);

    // ---- layers 2..3 ----
    for (int l = 0; l < 2; ++l) {
        gemm_mfma_kernel<<<gemmGrid, 256, 0, stream>>>(buf_h, N, nTiles, Wt_h, b1_h, b3_h, wsum, buf_a, buf_d);
        aggregate_ln_kernel<<<nodeWaveBlocks, 256, 0, stream>>>(rowptr, csr, buf_a, buf_d, g2, beta2, buf_h, N);
    }

    // ---- output layer ----
    out_gemv_kernel<<<nodeWaveBlocks, 256, 0, stream>>>(buf_h, N, W1_o, b1_o, W2_o, W3_o, b3_o, wsum, a1, dpart);
    gather_out_kernel<<<nBlocks, 256, 0, stream>>>(rowptr, csr, a1, dpart, (float*)d_out, N);
}

// Round 6
// 390.379 us; speedup vs baseline: 3.4479x; 1.1188x over previous
//
#include <hip/hip_runtime.h>
#include <hip/hip_bf16.h>
#include <math.h>

// ---------------------------------------------------------------------------
// GNN_72103910966081: 4-layer LEConv GNN, N=50000, E=600000, D=128.
// Round 6: aggregate_ln 8-wide edge unroll (8 independent row gathers in
// flight vs 2) — attacks the exposed-latency profile R5 showed
// (VALU 33%, HBM 22%, nothing saturated). gather_out 4-wide.
// ---------------------------------------------------------------------------

typedef _Float16 f16x8 __attribute__((ext_vector_type(8)));
typedef _Float16 f16x2 __attribute__((ext_vector_type(2)));
typedef float f32x4 __attribute__((ext_vector_type(4)));

#define LSTRIDE 136   // halves per LDS row: 128 + 8 (16B-aligned, breaks 2^k banks)

__device__ inline float wave_reduce_sum(float v) {
    #pragma unroll
    for (int off = 32; off > 0; off >>= 1)
        v += __shfl_xor(v, off, 64);
    return v;
}

// ===================== CSR build =====================

__global__ __launch_bounds__(256) void hist_kernel(
    const int* __restrict__ dst, int* __restrict__ deg, int E)
{
    int e = blockIdx.x * 256 + threadIdx.x;
    if (e < E) atomicAdd(&deg[dst[e]], 1);
}

__global__ __launch_bounds__(256) void scan_pass1(
    const int* __restrict__ deg, int N, int* __restrict__ partial)
{
    __shared__ int sh[256];
    int t = threadIdx.x;
    int base = blockIdx.x * 1024 + t * 4;
    int s = 0;
    #pragma unroll
    for (int i = 0; i < 4; ++i) { int idx = base + i; if (idx < N) s += deg[idx]; }
    sh[t] = s; __syncthreads();
    for (int off = 128; off > 0; off >>= 1) {
        if (t < off) sh[t] += sh[t + off];
        __syncthreads();
    }
    if (t == 0) partial[blockIdx.x] = sh[0];
}

__global__ __launch_bounds__(256) void scan_pass2(int* __restrict__ partial, int nb)
{
    __shared__ int sh[256];
    int t = threadIdx.x;
    sh[t] = (t < nb) ? partial[t] : 0;
    __syncthreads();
    for (int off = 1; off < 256; off <<= 1) {
        int x = sh[t];
        if (t >= off) x += sh[t - off];
        __syncthreads();
        sh[t] = x;
        __syncthreads();
    }
    if (t < nb) partial[t] = (t > 0) ? sh[t - 1] : 0;   // exclusive
}

__global__ __launch_bounds__(256) void scan_pass3(
    const int* __restrict__ deg, int N, const int* __restrict__ partial,
    int* __restrict__ rowptr, int* __restrict__ fill, int E)
{
    __shared__ int sh[256];
    int t = threadIdx.x;
    int base = blockIdx.x * 1024 + t * 4;
    int v[4]; int s = 0;
    #pragma unroll
    for (int i = 0; i < 4; ++i) { int idx = base + i; v[i] = (idx < N) ? deg[idx] : 0; s += v[i]; }
    sh[t] = s; __syncthreads();
    for (int off = 1; off < 256; off <<= 1) {
        int x = sh[t];
        if (t >= off) x += sh[t - off];
        __syncthreads();
        sh[t] = x;
        __syncthreads();
    }
    int off0 = partial[blockIdx.x] + ((t > 0) ? sh[t - 1] : 0);
    #pragma unroll
    for (int i = 0; i < 4; ++i) {
        int idx = base + i;
        if (idx < N) { rowptr[idx] = off0; fill[idx] = off0; off0 += v[i]; }
    }
    if (blockIdx.x == 0 && t == 0) rowptr[N] = E;
}

__global__ __launch_bounds__(256) void csr_fill_kernel(
    const int* __restrict__ src, const int* __restrict__ dst,
    const float* __restrict__ ew, int* __restrict__ fill,
    int2* __restrict__ csr, int E)
{
    int e = blockIdx.x * 256 + threadIdx.x;
    if (e >= E) return;
    int d = dst[e];
    int pos = atomicAdd(&fill[d], 1);
    csr[pos] = make_int2(src[e], __float_as_int(ew[e]));
}

__global__ __launch_bounds__(256) void wsum_csr_kernel(
    const int* __restrict__ rowptr, const int2* __restrict__ csr,
    float* __restrict__ wsum, int N)
{
    int n = blockIdx.x * 256 + threadIdx.x;
    if (n >= N) return;
    int b = rowptr[n], en = rowptr[n + 1];
    float s = 0.f;
    for (int e = b; e < en; ++e) s += __int_as_float(csr[e].y);
    wsum[n] = s;
}

// ===================== weight convert+transpose (fp32 [k][n] -> fp16 [n][k]) ==

__global__ __launch_bounds__(256) void convert_weights_kernel(
    const float* __restrict__ W1, const float* __restrict__ W2,
    const float* __restrict__ W3, _Float16* __restrict__ Wt)
{
    int idx = blockIdx.x * 256 + threadIdx.x;   // over 384*128
    if (idx >= 384 * 128) return;
    int n = idx >> 7, k = idx & 127;
    const float* W = (n < 128) ? W1 : (n < 256) ? W2 : W3;
    int c = n & 127;
    Wt[idx] = (_Float16)W[k * 128 + c];
}

// ===================== input standardization =====================

__global__ __launch_bounds__(256) void colstats_kernel(
    const float* __restrict__ x, int N, float* __restrict__ sums,
    float* __restrict__ sumsq)
{
    __shared__ float ls[256], lss[256];
    int t = threadIdx.x;
    int f = t & 127;
    int rstart = blockIdx.x * 2 + (t >> 7);
    int stride = gridDim.x * 2;
    float s = 0.f, ss = 0.f;
    for (int r = rstart; r < N; r += stride) {
        float v = x[(size_t)r * 128 + f];
        s += v; ss += v * v;
    }
    ls[t] = s; lss[t] = ss;
    __syncthreads();
    if (t < 128) {
        atomicAdd(&sums[t], ls[t] + ls[t + 128]);
        atomicAdd(&sumsq[t], lss[t] + lss[t + 128]);
    }
}

__global__ void finalize_stats_kernel(const float* __restrict__ sums,
                                      const float* __restrict__ sumsq, int N,
                                      float* __restrict__ mean,
                                      float* __restrict__ rstd)
{
    int f = threadIdx.x;  // 128 threads
    float s = sums[f], ss = sumsq[f];
    float m = s / (float)N;
    float var = (ss - s * s / (float)N) / (float)(N - 1);  // ddof=1
    var = fmaxf(var, 0.f);
    mean[f] = m;
    rstd[f] = 1.f / (sqrtf(var) + 1e-6f);
}

__global__ __launch_bounds__(256) void standardize_kernel(
    const float* __restrict__ x, const float* __restrict__ mean,
    const float* __restrict__ rstd, _Float16* __restrict__ out, long long total)
{
    long long i = (long long)blockIdx.x * blockDim.x + threadIdx.x;
    if (i >= total) return;
    int f = (int)(i & 127);
    out[i] = (_Float16)((x[i] - mean[f]) * rstd[f]);
}

// ===================== MFMA fused GEMM (persistent, B in registers) ========

__global__ __launch_bounds__(256, 2) void gemm_mfma_kernel(
    const _Float16* __restrict__ h, int N, int nTiles,
    const _Float16* __restrict__ Wt,
    const float* __restrict__ b1,
    const float* __restrict__ b3,
    const float* __restrict__ wsum,
    _Float16* __restrict__ out_a, _Float16* __restrict__ out_d)
{
    __shared__ _Float16 ldsS[64 * LSTRIDE];   // staged A tile
    __shared__ _Float16 lds_a[64 * LSTRIDE];  // epilogue a
    __shared__ _Float16 lds_d[64 * LSTRIDE];  // epilogue d

    int t = threadIdx.x;
    int wave = t >> 6;
    int lane = t & 63;
    int quad = lane >> 4;     // 0..3
    int c16  = lane & 15;     // 0..15

    // ---- B fragments: 6 n-tiles x 4 k-steps, in registers for the kernel's life
    const f16x8* wv = (const f16x8*)Wt;  // row (n) stride 16 chunks
    int ntl[6] = {2*wave, 2*wave+1, 8+2*wave, 9+2*wave, 16+2*wave, 17+2*wave};
    f16x8 bfrag[6][4];
    #pragma unroll
    for (int j = 0; j < 6; ++j) {
        int nrow = ntl[j] * 16 + c16;
        #pragma unroll
        for (int s = 0; s < 4; ++s)
            bfrag[j][s] = wv[(size_t)nrow * 16 + s * 4 + quad];
    }
    float bb1[2], bb3[2];
    #pragma unroll
    for (int j = 0; j < 2; ++j) {
        int col = (2*wave + j) * 16 + c16;
        bb1[j] = b1[col];
        bb3[j] = b3[col];
    }

    const f16x8* hv = (const f16x8*)h;   // row stride 16 chunks
    f16x8* oa = (f16x8*)out_a;
    f16x8* od = (f16x8*)out_d;

    for (int tile = blockIdx.x; tile < nTiles; tile += gridDim.x) {
        int row0 = tile * 64;

        // ---- stage A tile (64 rows x 256B) into LDS, fully coalesced
        #pragma unroll
        for (int i = 0; i < 4; ++i) {
            int idx = i * 256 + t;        // 0..1023
            int row = idx >> 4;
            int chunk = idx & 15;
            int grow = row0 + row;
            if (grow >= N) grow = N - 1;  // clamp; per-row results discarded later
            *(f16x8*)&ldsS[row * LSTRIDE + chunk * 8] = hv[(size_t)grow * 16 + chunk];
        }
        __syncthreads();

        // ---- 4 row-groups of 16 rows each
        #pragma unroll
        for (int r = 0; r < 4; ++r) {
            f16x8 afrag[4];
            #pragma unroll
            for (int s = 0; s < 4; ++s)
                afrag[s] = *(const f16x8*)&ldsS[(r*16 + c16) * LSTRIDE + (s*4 + quad) * 8];

            f32x4 acc[6];
            #pragma unroll
            for (int j = 0; j < 6; ++j) acc[j] = (f32x4){0.f, 0.f, 0.f, 0.f};
            #pragma unroll
            for (int s = 0; s < 4; ++s) {
                #pragma unroll
                for (int j = 0; j < 6; ++j)
                    acc[j] = __builtin_amdgcn_mfma_f32_16x16x32_f16(afrag[s], bfrag[j][s], acc[j], 0, 0, 0);
            }

            // epilogue -> LDS (C/D layout: col=c16, row=quad*4+reg)
            float wsv[4];
            #pragma unroll
            for (int reg = 0; reg < 4; ++reg) {
                int gr = row0 + r*16 + quad*4 + reg;
                wsv[reg] = wsum[(gr < N) ? gr : (N - 1)];
            }
            #pragma unroll
            for (int j = 0; j < 2; ++j) {
                int col = (2*wave + j) * 16 + c16;
                #pragma unroll
                for (int reg = 0; reg < 4; ++reg) {
                    int lr = r*16 + quad*4 + reg;
                    lds_a[lr * LSTRIDE + col] = (_Float16)(acc[j][reg] + bb1[j]);
                    lds_d[lr * LSTRIDE + col] =
                        (_Float16)(acc[4+j][reg] + bb3[j] - wsv[reg] * acc[2+j][reg]);
                }
            }
        }
        __syncthreads();

        // ---- coalesced stores (64 rows x 16 chunks of 16B, both buffers)
        #pragma unroll
        for (int i = 0; i < 4; ++i) {
            int idx = i * 256 + t;
            int row = idx >> 4;
            int c8  = idx & 15;
            int grow = row0 + row;
            if (grow < N) {
                f16x8 va = *(const f16x8*)&lds_a[row * LSTRIDE + c8 * 8];
                oa[(size_t)grow * 16 + c8] = va;
                f16x8 vd = *(const f16x8*)&lds_d[row * LSTRIDE + c8 * 8];
                od[(size_t)grow * 16 + c8] = vd;
            }
        }
        __syncthreads();   // protect ldsS/lds_* before next iteration's writes
    }
}

// ===================== fused gather + LN + leaky (fp16 a/d, fp16 h out) =====
// 8-wide edge unroll: 8 independent row gathers in flight per iteration.

__global__ __launch_bounds__(256) void aggregate_ln_kernel(
    const int* __restrict__ rowptr, const int2* __restrict__ csr,
    const _Float16* __restrict__ a, const _Float16* __restrict__ d,
    const float* __restrict__ g, const float* __restrict__ beta,
    _Float16* __restrict__ out, int N)
{
    int wave = threadIdx.x >> 6;
    int lane = threadIdx.x & 63;
    int node = blockIdx.x * 4 + wave;
    if (node >= N) return;
    int b = rowptr[node], en = rowptr[node + 1];
    float acc0 = 0.f, acc1 = 0.f;
    const f16x2* av = (const f16x2*)a;   // row stride 64

    int e = b;
    for (; e + 8 <= en; e += 8) {
        int2 p[8];
        #pragma unroll
        for (int j = 0; j < 8; ++j) p[j] = csr[e + j];
        f16x2 v[8];
        #pragma unroll
        for (int j = 0; j < 8; ++j) v[j] = av[(size_t)p[j].x * 64 + lane];
        #pragma unroll
        for (int j = 0; j < 8; ++j) {
            float w = __int_as_float(p[j].y);
            acc0 += w * (float)v[j].x;
            acc1 += w * (float)v[j].y;
        }
    }
    for (; e + 2 <= en; e += 2) {
        int2 p0 = csr[e], p1 = csr[e + 1];
        f16x2 v0 = av[(size_t)p0.x * 64 + lane];
        f16x2 v1 = av[(size_t)p1.x * 64 + lane];
        float w0 = __int_as_float(p0.y), w1 = __int_as_float(p1.y);
        acc0 += w0 * (float)v0.x + w1 * (float)v1.x;
        acc1 += w0 * (float)v0.y + w1 * (float)v1.y;
    }
    if (e < en) {
        int2 p = csr[e];
        f16x2 v = av[(size_t)p.x * 64 + lane];
        float w = __int_as_float(p.y);
        acc0 += w * (float)v.x;
        acc1 += w * (float)v.y;
    }

    f16x2 dv = ((const f16x2*)d)[(size_t)node * 64 + lane];
    float v0 = acc0 + (float)dv.x, v1 = acc1 + (float)dv.y;
    float s  = wave_reduce_sum(v0 + v1);
    float ss = wave_reduce_sum(v0 * v0 + v1 * v1);
    float mean = s * (1.f / 128.f);
    float var = ss * (1.f / 128.f) - mean * mean;
    float rstd = rsqrtf(var + 1e-5f);
    float2 gv = ((const float2*)g)[lane];
    float2 bv = ((const float2*)beta)[lane];
    float o0 = (v0 - mean) * rstd * gv.x + bv.x;
    float o1 = (v1 - mean) * rstd * gv.y + bv.y;
    o0 = o0 >= 0.f ? o0 : 0.1f * o0;
    o1 = o1 >= 0.f ? o1 : 0.1f * o1;
    f16x2 ov; ov.x = (_Float16)o0; ov.y = (_Float16)o1;
    ((f16x2*)out)[(size_t)node * 64 + lane] = ov;
}

// ===================== output layer (D_OUT=1) =====================

__global__ __launch_bounds__(256) void out_gemv_kernel(
    const _Float16* __restrict__ h, int N,
    const float* __restrict__ W1, const float* __restrict__ b1,
    const float* __restrict__ W2,
    const float* __restrict__ W3, const float* __restrict__ b3,
    const float* __restrict__ wsum,
    float* __restrict__ a1, float* __restrict__ dpart)
{
    int wave = threadIdx.x >> 6;
    int lane = threadIdx.x & 63;
    int node = blockIdx.x * 4 + wave;
    if (node >= N) return;
    const _Float16* row = h + (size_t)node * 128;
    float h0 = (float)row[lane], h1 = (float)row[lane + 64];
    float s1 = wave_reduce_sum(h0 * W1[lane] + h1 * W1[lane + 64]);
    float s2 = wave_reduce_sum(h0 * W2[lane] + h1 * W2[lane + 64]);
    float s3 = wave_reduce_sum(h0 * W3[lane] + h1 * W3[lane + 64]);
    if (lane == 0) {
        a1[node] = s1 + b1[0];
        dpart[node] = s3 + b3[0] - wsum[node] * s2;
    }
}

__global__ __launch_bounds__(256) void gather_out_kernel(
    const int* __restrict__ rowptr, const int2* __restrict__ csr,
    const float* __restrict__ a1, const float* __restrict__ dpart,
    float* __restrict__ out, int N)
{
    int n = blockIdx.x * 256 + threadIdx.x;
    if (n >= N) return;
    int b = rowptr[n], en = rowptr[n + 1];
    float s = dpart[n];
    int e = b;
    for (; e + 4 <= en; e += 4) {
        int2 p0 = csr[e], p1 = csr[e+1], p2 = csr[e+2], p3 = csr[e+3];
        float x0 = a1[p0.x], x1 = a1[p1.x], x2 = a1[p2.x], x3 = a1[p3.x];
        s += __int_as_float(p0.y) * x0 + __int_as_float(p1.y) * x1
           + __int_as_float(p2.y) * x2 + __int_as_float(p3.y) * x3;
    }
    for (; e < en; ++e) {
        int2 p = csr[e];
        s += __int_as_float(p.y) * a1[p.x];
    }
    out[n] = 1.f / (1.f + expf(-s));
}

// ---------------------------------------------------------------------------
extern "C" void kernel_launch(void* const* d_in, const int* in_sizes, int n_in,
                              void* d_out, int out_size, void* d_ws, size_t ws_size,
                              hipStream_t stream)
{
    const float* x     = (const float*)d_in[0];
    const float* ew    = (const float*)d_in[1];
    const float* W1_in = (const float*)d_in[2];
    const float* b1_in = (const float*)d_in[3];
    const float* W2_in = (const float*)d_in[4];
    const float* W3_in = (const float*)d_in[5];
    const float* b3_in = (const float*)d_in[6];
    const float* W1_h  = (const float*)d_in[7];
    const float* b1_h  = (const float*)d_in[8];
    const float* W2_h  = (const float*)d_in[9];
    const float* W3_h  = (const float*)d_in[10];
    const float* b3_h  = (const float*)d_in[11];
    const float* W1_o  = (const float*)d_in[12];
    const float* b1_o  = (const float*)d_in[13];
    const float* W2_o  = (const float*)d_in[14];
    const float* W3_o  = (const float*)d_in[15];
    const float* b3_o  = (const float*)d_in[16];
    const float* g1    = (const float*)d_in[17];
    const float* beta1 = (const float*)d_in[18];
    const float* g2    = (const float*)d_in[19];
    const float* beta2 = (const float*)d_in[20];
    const int*   eidx  = (const int*)d_in[21];

    const int N = in_sizes[0] / 128;
    const int E = in_sizes[1];
    const int* srcp = eidx;
    const int* dstp = eidx + E;

    // ---- workspace carve-out (256B-aligned chunks) ----
    size_t off = 0;
    auto carve = [&](size_t nbytes) -> void* {
        void* p = (char*)d_ws + off;
        off += (nbytes + 255) & ~(size_t)255;
        return p;
    };
    _Float16* buf_h  = (_Float16*)carve((size_t)N * 128 * 2);
    _Float16* buf_a  = (_Float16*)carve((size_t)N * 128 * 2);
    _Float16* buf_d  = (_Float16*)carve((size_t)N * 128 * 2);
    int2*     csr    = (int2*)    carve((size_t)E * 8);
    _Float16* Wt_in  = (_Float16*)carve(384 * 128 * 2);
    _Float16* Wt_h   = (_Float16*)carve(384 * 128 * 2);
    int*      deg    = (int*)     carve((size_t)N * 4);
    int*      rowptr = (int*)     carve((size_t)(N + 1) * 4);
    int*      fill   = (int*)     carve((size_t)N * 4);
    int*      partial= (int*)     carve(256 * 4);
    float*    stats  = (float*)   carve(256 * 4);
    float*    meanp  = (float*)   carve(128 * 4);
    float*    rstdp  = (float*)   carve(128 * 4);
    float*    wsum   = (float*)   carve((size_t)N * 4);
    float*    a1     = (float*)   carve((size_t)N * 4);
    float*    dpart  = (float*)   carve((size_t)N * 4);

    const long long totNF = (long long)N * 128;
    const int nodeWaveBlocks = (N + 3) / 4;
    const int eBlocks = (E + 255) / 256;
    const int nBlocks = (N + 255) / 256;
    const int nb = (N + 1023) / 1024;
    const int wBlocks = (384 * 128 + 255) / 256;

    hipMemsetAsync(deg, 0, (size_t)N * 4, stream);
    hipMemsetAsync(stats, 0, 256 * 4, stream);

    // ---- CSR build + weight conversion ----
    hist_kernel<<<eBlocks, 256, 0, stream>>>(dstp, deg, E);
    scan_pass1<<<nb, 256, 0, stream>>>(deg, N, partial);
    scan_pass2<<<1, 256, 0, stream>>>(partial, nb);
    scan_pass3<<<nb, 256, 0, stream>>>(deg, N, partial, rowptr, fill, E);
    csr_fill_kernel<<<eBlocks, 256, 0, stream>>>(srcp, dstp, ew, fill, csr, E);
    wsum_csr_kernel<<<nBlocks, 256, 0, stream>>>(rowptr, csr, wsum, N);
    convert_weights_kernel<<<wBlocks, 256, 0, stream>>>(W1_in, W2_in, W3_in, Wt_in);
    convert_weights_kernel<<<wBlocks, 256, 0, stream>>>(W1_h, W2_h, W3_h, Wt_h);

    // ---- input standardization (writes fp16 h) ----
    colstats_kernel<<<256, 256, 0, stream>>>(x, N, stats, stats + 128);
    finalize_stats_kernel<<<1, 128, 0, stream>>>(stats, stats + 128, N, meanp, rstdp);
    standardize_kernel<<<(int)((totNF + 255) / 256), 256, 0, stream>>>(x, meanp, rstdp, buf_h, totNF);

    const int nTiles = (N + 63) / 64;
    const int gemmGrid = (nTiles < 512) ? nTiles : 512;

    // ---- layer 1 ----
    gemm_mfma_kernel<<<gemmGrid, 256, 0, stream>>>(buf_h, N, nTiles, Wt_in, b1_in, b3_in, wsum, buf_a, buf_d);
    aggregate_ln_kernel<<<nodeWaveBlocks, 256, 0, stream>>>(rowptr, csr, buf_a, buf_d, g1, beta1, buf_h, N);

    // ---- layers 2..3 ----
    for (int l = 0; l < 2; ++l) {
        gemm_mfma_kernel<<<gemmGrid, 256, 0, stream>>>(buf_h, N, nTiles, Wt_h, b1_h, b3_h, wsum, buf_a, buf_d);
        aggregate_ln_kernel<<<nodeWaveBlocks, 256, 0, stream>>>(rowptr, csr, buf_a, buf_d, g2, beta2, buf_h, N);
    }

    // ---- output layer ----
    out_gemv_kernel<<<nodeWaveBlocks, 256, 0, stream>>>(buf_h, N, W1_o, b1_o, W2_o, W3_o, b3_o, wsum, a1, dpart);
    gather_out_kernel<<<nBlocks, 256, 0, stream>>>(rowptr, csr, a1, dpart, (float*)d_out, N);
}

// Round 7
// 381.778 us; speedup vs baseline: 3.5256x; 1.0225x over previous
//
#include <hip/hip_runtime.h>
#include <hip/hip_bf16.h>
#include <math.h>

// ---------------------------------------------------------------------------
// GNN_72103910966081: 4-layer LEConv GNN, N=50000, E=600000, D=128.
// Round 7: (1) colstats rewrite — coalesced float4 sweeps + partials buffer
// (was 44.6us @ 293GB/s latency-bound); (2) aggregate_ln 2 nodes/wave
// (f16x4 per 32-lane half: 512B in flight per gather instr, half the instrs).
// ---------------------------------------------------------------------------

typedef _Float16 f16x8 __attribute__((ext_vector_type(8)));
typedef _Float16 f16x4 __attribute__((ext_vector_type(4)));
typedef _Float16 f16x2 __attribute__((ext_vector_type(2)));
typedef float f32x4 __attribute__((ext_vector_type(4)));

#define LSTRIDE 136   // halves per LDS row: 128 + 8 (16B-aligned, breaks 2^k banks)

__device__ inline float wave_reduce_sum(float v) {
    #pragma unroll
    for (int off = 32; off > 0; off >>= 1)
        v += __shfl_xor(v, off, 64);
    return v;
}

// ===================== CSR build =====================

__global__ __launch_bounds__(256) void hist_kernel(
    const int* __restrict__ dst, int* __restrict__ deg, int E)
{
    int e = blockIdx.x * 256 + threadIdx.x;
    if (e < E) atomicAdd(&deg[dst[e]], 1);
}

__global__ __launch_bounds__(256) void scan_pass1(
    const int* __restrict__ deg, int N, int* __restrict__ partial)
{
    __shared__ int sh[256];
    int t = threadIdx.x;
    int base = blockIdx.x * 1024 + t * 4;
    int s = 0;
    #pragma unroll
    for (int i = 0; i < 4; ++i) { int idx = base + i; if (idx < N) s += deg[idx]; }
    sh[t] = s; __syncthreads();
    for (int off = 128; off > 0; off >>= 1) {
        if (t < off) sh[t] += sh[t + off];
        __syncthreads();
    }
    if (t == 0) partial[blockIdx.x] = sh[0];
}

__global__ __launch_bounds__(256) void scan_pass2(int* __restrict__ partial, int nb)
{
    __shared__ int sh[256];
    int t = threadIdx.x;
    sh[t] = (t < nb) ? partial[t] : 0;
    __syncthreads();
    for (int off = 1; off < 256; off <<= 1) {
        int x = sh[t];
        if (t >= off) x += sh[t - off];
        __syncthreads();
        sh[t] = x;
        __syncthreads();
    }
    if (t < nb) partial[t] = (t > 0) ? sh[t - 1] : 0;   // exclusive
}

__global__ __launch_bounds__(256) void scan_pass3(
    const int* __restrict__ deg, int N, const int* __restrict__ partial,
    int* __restrict__ rowptr, int* __restrict__ fill, int E)
{
    __shared__ int sh[256];
    int t = threadIdx.x;
    int base = blockIdx.x * 1024 + t * 4;
    int v[4]; int s = 0;
    #pragma unroll
    for (int i = 0; i < 4; ++i) { int idx = base + i; v[i] = (idx < N) ? deg[idx] : 0; s += v[i]; }
    sh[t] = s; __syncthreads();
    for (int off = 1; off < 256; off <<= 1) {
        int x = sh[t];
        if (t >= off) x += sh[t - off];
        __syncthreads();
        sh[t] = x;
        __syncthreads();
    }
    int off0 = partial[blockIdx.x] + ((t > 0) ? sh[t - 1] : 0);
    #pragma unroll
    for (int i = 0; i < 4; ++i) {
        int idx = base + i;
        if (idx < N) { rowptr[idx] = off0; fill[idx] = off0; off0 += v[i]; }
    }
    if (blockIdx.x == 0 && t == 0) rowptr[N] = E;
}

__global__ __launch_bounds__(256) void csr_fill_kernel(
    const int* __restrict__ src, const int* __restrict__ dst,
    const float* __restrict__ ew, int* __restrict__ fill,
    int2* __restrict__ csr, int E)
{
    int e = blockIdx.x * 256 + threadIdx.x;
    if (e >= E) return;
    int d = dst[e];
    int pos = atomicAdd(&fill[d], 1);
    csr[pos] = make_int2(src[e], __float_as_int(ew[e]));
}

__global__ __launch_bounds__(256) void wsum_csr_kernel(
    const int* __restrict__ rowptr, const int2* __restrict__ csr,
    float* __restrict__ wsum, int N)
{
    int n = blockIdx.x * 256 + threadIdx.x;
    if (n >= N) return;
    int b = rowptr[n], en = rowptr[n + 1];
    float s = 0.f;
    for (int e = b; e < en; ++e) s += __int_as_float(csr[e].y);
    wsum[n] = s;
}

// ===================== weight convert+transpose (fp32 [k][n] -> fp16 [n][k]) ==

__global__ __launch_bounds__(256) void convert_weights_kernel(
    const float* __restrict__ W1, const float* __restrict__ W2,
    const float* __restrict__ W3, _Float16* __restrict__ Wt)
{
    int idx = blockIdx.x * 256 + threadIdx.x;   // over 384*128
    if (idx >= 384 * 128) return;
    int n = idx >> 7, k = idx & 127;
    const float* W = (n < 128) ? W1 : (n < 256) ? W2 : W3;
    int c = n & 127;
    Wt[idx] = (_Float16)W[k * 128 + c];
}

// ===================== input standardization (coalesced, partials) =========
// 512 blocks; thread (g=t>>5, c=t&31) sweeps rows blk*8+g (+4096 stride),
// reading float4 at col-chunk c. Block reduces 8 row-groups in LDS, writes
// per-block column partials (no atomics).

#define CS_BLOCKS 512

__global__ __launch_bounds__(256) void colstats_kernel(
    const float* __restrict__ x, int N,
    float* __restrict__ ps, float* __restrict__ pss)   // [CS_BLOCKS][128] each
{
    __shared__ float shs[256][4];
    __shared__ float shq[256][4];
    int t = threadIdx.x;
    int g = t >> 5;
    int c = t & 31;
    const float4* xv = (const float4*)x;    // row stride 32
    float s0=0.f,s1=0.f,s2=0.f,s3=0.f, q0=0.f,q1=0.f,q2=0.f,q3=0.f;
    for (int r = blockIdx.x * 8 + g; r < N; r += CS_BLOCKS * 8) {
        float4 v = xv[(size_t)r * 32 + c];
        s0 += v.x; s1 += v.y; s2 += v.z; s3 += v.w;
        q0 += v.x*v.x; q1 += v.y*v.y; q2 += v.z*v.z; q3 += v.w*v.w;
    }
    shs[t][0]=s0; shs[t][1]=s1; shs[t][2]=s2; shs[t][3]=s3;
    shq[t][0]=q0; shq[t][1]=q1; shq[t][2]=q2; shq[t][3]=q3;
    __syncthreads();
    if (t < 32) {
        float S[4] = {0,0,0,0}, Q[4] = {0,0,0,0};
        #pragma unroll
        for (int gg = 0; gg < 8; ++gg) {
            #pragma unroll
            for (int i = 0; i < 4; ++i) {
                S[i] += shs[t + 32*gg][i];
                Q[i] += shq[t + 32*gg][i];
            }
        }
        #pragma unroll
        for (int i = 0; i < 4; ++i) {
            ps [blockIdx.x * 128 + t*4 + i] = S[i];
            pss[blockIdx.x * 128 + t*4 + i] = Q[i];
        }
    }
}

__global__ __launch_bounds__(256) void reduce_stats_kernel(
    const float* __restrict__ ps, const float* __restrict__ pss, int N,
    float* __restrict__ mean, float* __restrict__ rstd)
{
    __shared__ float sh[256];
    int t = threadIdx.x;           // 256
    int f = t & 127;
    const float* src = (t >= 128) ? pss : ps;
    float s = 0.f;
    for (int r = 0; r < CS_BLOCKS; ++r) s += src[r * 128 + f];
    sh[t] = s;
    __syncthreads();
    if (t < 128) {
        float sum = sh[t], sumsq = sh[t + 128];
        float m = sum / (float)N;
        float var = (sumsq - sum * sum / (float)N) / (float)(N - 1);  // ddof=1
        var = fmaxf(var, 0.f);
        mean[t] = m;
        rstd[t] = 1.f / (sqrtf(var) + 1e-6f);
    }
}

__global__ __launch_bounds__(256) void standardize_kernel(
    const float* __restrict__ x, const float* __restrict__ mean,
    const float* __restrict__ rstd, _Float16* __restrict__ out, long long total)
{
    long long i = (long long)blockIdx.x * blockDim.x + threadIdx.x;
    if (i >= total) return;
    int f = (int)(i & 127);
    out[i] = (_Float16)((x[i] - mean[f]) * rstd[f]);
}

// ===================== MFMA fused GEMM (persistent, B in registers) ========

__global__ __launch_bounds__(256, 2) void gemm_mfma_kernel(
    const _Float16* __restrict__ h, int N, int nTiles,
    const _Float16* __restrict__ Wt,
    const float* __restrict__ b1,
    const float* __restrict__ b3,
    const float* __restrict__ wsum,
    _Float16* __restrict__ out_a, _Float16* __restrict__ out_d)
{
    __shared__ _Float16 ldsS[64 * LSTRIDE];   // staged A tile
    __shared__ _Float16 lds_a[64 * LSTRIDE];  // epilogue a
    __shared__ _Float16 lds_d[64 * LSTRIDE];  // epilogue d

    int t = threadIdx.x;
    int wave = t >> 6;
    int lane = t & 63;
    int quad = lane >> 4;     // 0..3
    int c16  = lane & 15;     // 0..15

    // ---- B fragments: 6 n-tiles x 4 k-steps, in registers for the kernel's life
    const f16x8* wv = (const f16x8*)Wt;  // row (n) stride 16 chunks
    int ntl[6] = {2*wave, 2*wave+1, 8+2*wave, 9+2*wave, 16+2*wave, 17+2*wave};
    f16x8 bfrag[6][4];
    #pragma unroll
    for (int j = 0; j < 6; ++j) {
        int nrow = ntl[j] * 16 + c16;
        #pragma unroll
        for (int s = 0; s < 4; ++s)
            bfrag[j][s] = wv[(size_t)nrow * 16 + s * 4 + quad];
    }
    float bb1[2], bb3[2];
    #pragma unroll
    for (int j = 0; j < 2; ++j) {
        int col = (2*wave + j) * 16 + c16;
        bb1[j] = b1[col];
        bb3[j] = b3[col];
    }

    const f16x8* hv = (const f16x8*)h;   // row stride 16 chunks
    f16x8* oa = (f16x8*)out_a;
    f16x8* od = (f16x8*)out_d;

    for (int tile = blockIdx.x; tile < nTiles; tile += gridDim.x) {
        int row0 = tile * 64;

        // ---- stage A tile (64 rows x 256B) into LDS, fully coalesced
        #pragma unroll
        for (int i = 0; i < 4; ++i) {
            int idx = i * 256 + t;        // 0..1023
            int row = idx >> 4;
            int chunk = idx & 15;
            int grow = row0 + row;
            if (grow >= N) grow = N - 1;  // clamp; per-row results discarded later
            *(f16x8*)&ldsS[row * LSTRIDE + chunk * 8] = hv[(size_t)grow * 16 + chunk];
        }
        __syncthreads();

        // ---- 4 row-groups of 16 rows each
        #pragma unroll
        for (int r = 0; r < 4; ++r) {
            f16x8 afrag[4];
            #pragma unroll
            for (int s = 0; s < 4; ++s)
                afrag[s] = *(const f16x8*)&ldsS[(r*16 + c16) * LSTRIDE + (s*4 + quad) * 8];

            f32x4 acc[6];
            #pragma unroll
            for (int j = 0; j < 6; ++j) acc[j] = (f32x4){0.f, 0.f, 0.f, 0.f};
            #pragma unroll
            for (int s = 0; s < 4; ++s) {
                #pragma unroll
                for (int j = 0; j < 6; ++j)
                    acc[j] = __builtin_amdgcn_mfma_f32_16x16x32_f16(afrag[s], bfrag[j][s], acc[j], 0, 0, 0);
            }

            // epilogue -> LDS (C/D layout: col=c16, row=quad*4+reg)
            float wsv[4];
            #pragma unroll
            for (int reg = 0; reg < 4; ++reg) {
                int gr = row0 + r*16 + quad*4 + reg;
                wsv[reg] = wsum[(gr < N) ? gr : (N - 1)];
            }
            #pragma unroll
            for (int j = 0; j < 2; ++j) {
                int col = (2*wave + j) * 16 + c16;
                #pragma unroll
                for (int reg = 0; reg < 4; ++reg) {
                    int lr = r*16 + quad*4 + reg;
                    lds_a[lr * LSTRIDE + col] = (_Float16)(acc[j][reg] + bb1[j]);
                    lds_d[lr * LSTRIDE + col] =
                        (_Float16)(acc[4+j][reg] + bb3[j] - wsv[reg] * acc[2+j][reg]);
                }
            }
        }
        __syncthreads();

        // ---- coalesced stores (64 rows x 16 chunks of 16B, both buffers)
        #pragma unroll
        for (int i = 0; i < 4; ++i) {
            int idx = i * 256 + t;
            int row = idx >> 4;
            int c8  = idx & 15;
            int grow = row0 + row;
            if (grow < N) {
                f16x8 va = *(const f16x8*)&lds_a[row * LSTRIDE + c8 * 8];
                oa[(size_t)grow * 16 + c8] = va;
                f16x8 vd = *(const f16x8*)&lds_d[row * LSTRIDE + c8 * 8];
                od[(size_t)grow * 16 + c8] = vd;
            }
        }
        __syncthreads();   // protect ldsS/lds_* before next iteration's writes
    }
}

// ===================== fused gather + LN + leaky =====================
// 2 nodes per wave: lanes [0,32) node A, [32,64) node B; each lane holds
// f16x4 (8B) of its node's row => each gather instr fetches 512B (2 rows).
// 8-wide edge unroll => 16 edge-rows in flight per iteration.

__global__ __launch_bounds__(256) void aggregate_ln_kernel(
    const int* __restrict__ rowptr, const int2* __restrict__ csr,
    const _Float16* __restrict__ a, const _Float16* __restrict__ d,
    const float* __restrict__ g, const float* __restrict__ beta,
    _Float16* __restrict__ out, int N, int E)
{
    int wave = threadIdx.x >> 6;
    int lane = threadIdx.x & 63;
    int sub  = lane >> 5;        // which node of the pair
    int l    = lane & 31;        // feature chunk (cols 4l..4l+3)
    int node = blockIdx.x * 8 + wave * 2 + sub;
    bool active = node < N;
    int nodeC = active ? node : N - 1;
    int b = rowptr[nodeC], en = rowptr[nodeC + 1];
    if (!active) en = b;                       // no edges for padding lanes
    int deg = en - b;
    int degOther = __shfl_xor(deg, 32);
    int iters = deg > degOther ? deg : degOther;   // uniform per wave-half pair

    const f16x4* av = (const f16x4*)a;   // row stride 32
    float a0 = 0.f, a1 = 0.f, a2 = 0.f, a3 = 0.f;

    for (int k = 0; k < iters; k += 8) {
        int2 p[8];
        #pragma unroll
        for (int j = 0; j < 8; ++j) {
            int idx = b + k + j;
            int idc = (idx < en) ? idx : (E - 1);
            p[j] = csr[idc];
            if (idx >= en) p[j].y = 0;           // zero weight for overhang
        }
        f16x4 v[8];
        #pragma unroll
        for (int j = 0; j < 8; ++j)
            v[j] = av[(size_t)p[j].x * 32 + l];
        #pragma unroll
        for (int j = 0; j < 8; ++j) {
            float w = __int_as_float(p[j].y);
            a0 += w * (float)v[j].x;
            a1 += w * (float)v[j].y;
            a2 += w * (float)v[j].z;
            a3 += w * (float)v[j].w;
        }
    }

    f16x4 dv = ((const f16x4*)d)[(size_t)nodeC * 32 + l];
    float v0 = a0 + (float)dv.x, v1 = a1 + (float)dv.y;
    float v2 = a2 + (float)dv.z, v3 = a3 + (float)dv.w;

    // 32-lane (half-wave) reductions
    float s  = v0 + v1 + v2 + v3;
    float ss = v0*v0 + v1*v1 + v2*v2 + v3*v3;
    #pragma unroll
    for (int off = 16; off > 0; off >>= 1) {
        s  += __shfl_xor(s,  off, 64);
        ss += __shfl_xor(ss, off, 64);
    }
    float mean = s * (1.f / 128.f);
    float var = ss * (1.f / 128.f) - mean * mean;
    float rstd = rsqrtf(var + 1e-5f);

    float4 gv = ((const float4*)g)[l];
    float4 bv = ((const float4*)beta)[l];
    float o0 = (v0 - mean) * rstd * gv.x + bv.x;
    float o1 = (v1 - mean) * rstd * gv.y + bv.y;
    float o2 = (v2 - mean) * rstd * gv.z + bv.z;
    float o3 = (v3 - mean) * rstd * gv.w + bv.w;
    o0 = o0 >= 0.f ? o0 : 0.1f * o0;
    o1 = o1 >= 0.f ? o1 : 0.1f * o1;
    o2 = o2 >= 0.f ? o2 : 0.1f * o2;
    o3 = o3 >= 0.f ? o3 : 0.1f * o3;
    if (active) {
        f16x4 ov;
        ov.x = (_Float16)o0; ov.y = (_Float16)o1;
        ov.z = (_Float16)o2; ov.w = (_Float16)o3;
        ((f16x4*)out)[(size_t)node * 32 + l] = ov;
    }
}

// ===================== output layer (D_OUT=1) =====================

__global__ __launch_bounds__(256) void out_gemv_kernel(
    const _Float16* __restrict__ h, int N,
    const float* __restrict__ W1, const float* __restrict__ b1,
    const float* __restrict__ W2,
    const float* __restrict__ W3, const float* __restrict__ b3,
    const float* __restrict__ wsum,
    float* __restrict__ a1, float* __restrict__ dpart)
{
    int wave = threadIdx.x >> 6;
    int lane = threadIdx.x & 63;
    int node = blockIdx.x * 4 + wave;
    if (node >= N) return;
    const _Float16* row = h + (size_t)node * 128;
    float h0 = (float)row[lane], h1 = (float)row[lane + 64];
    float s1 = wave_reduce_sum(h0 * W1[lane] + h1 * W1[lane + 64]);
    float s2 = wave_reduce_sum(h0 * W2[lane] + h1 * W2[lane + 64]);
    float s3 = wave_reduce_sum(h0 * W3[lane] + h1 * W3[lane + 64]);
    if (lane == 0) {
        a1[node] = s1 + b1[0];
        dpart[node] = s3 + b3[0] - wsum[node] * s2;
    }
}

__global__ __launch_bounds__(256) void gather_out_kernel(
    const int* __restrict__ rowptr, const int2* __restrict__ csr,
    const float* __restrict__ a1, const float* __restrict__ dpart,
    float* __restrict__ out, int N)
{
    int n = blockIdx.x * 256 + threadIdx.x;
    if (n >= N) return;
    int b = rowptr[n], en = rowptr[n + 1];
    float s = dpart[n];
    int e = b;
    for (; e + 4 <= en; e += 4) {
        int2 p0 = csr[e], p1 = csr[e+1], p2 = csr[e+2], p3 = csr[e+3];
        float x0 = a1[p0.x], x1 = a1[p1.x], x2 = a1[p2.x], x3 = a1[p3.x];
        s += __int_as_float(p0.y) * x0 + __int_as_float(p1.y) * x1
           + __int_as_float(p2.y) * x2 + __int_as_float(p3.y) * x3;
    }
    for (; e < en; ++e) {
        int2 p = csr[e];
        s += __int_as_float(p.y) * a1[p.x];
    }
    out[n] = 1.f / (1.f + expf(-s));
}

// ---------------------------------------------------------------------------
extern "C" void kernel_launch(void* const* d_in, const int* in_sizes, int n_in,
                              void* d_out, int out_size, void* d_ws, size_t ws_size,
                              hipStream_t stream)
{
    const float* x     = (const float*)d_in[0];
    const float* ew    = (const float*)d_in[1];
    const float* W1_in = (const float*)d_in[2];
    const float* b1_in = (const float*)d_in[3];
    const float* W2_in = (const float*)d_in[4];
    const float* W3_in = (const float*)d_in[5];
    const float* b3_in = (const float*)d_in[6];
    const float* W1_h  = (const float*)d_in[7];
    const float* b1_h  = (const float*)d_in[8];
    const float* W2_h  = (const float*)d_in[9];
    const float* W3_h  = (const float*)d_in[10];
    const float* b3_h  = (const float*)d_in[11];
    const float* W1_o  = (const float*)d_in[12];
    const float* b1_o  = (const float*)d_in[13];
    const float* W2_o  = (const float*)d_in[14];
    const float* W3_o  = (const float*)d_in[15];
    const float* b3_o  = (const float*)d_in[16];
    const float* g1    = (const float*)d_in[17];
    const float* beta1 = (const float*)d_in[18];
    const float* g2    = (const float*)d_in[19];
    const float* beta2 = (const float*)d_in[20];
    const int*   eidx  = (const int*)d_in[21];

    const int N = in_sizes[0] / 128;
    const int E = in_sizes[1];
    const int* srcp = eidx;
    const int* dstp = eidx + E;

    // ---- workspace carve-out (256B-aligned chunks) ----
    size_t off = 0;
    auto carve = [&](size_t nbytes) -> void* {
        void* p = (char*)d_ws + off;
        off += (nbytes + 255) & ~(size_t)255;
        return p;
    };
    _Float16* buf_h  = (_Float16*)carve((size_t)N * 128 * 2);
    _Float16* buf_a  = (_Float16*)carve((size_t)N * 128 * 2);
    _Float16* buf_d  = (_Float16*)carve((size_t)N * 128 * 2);
    int2*     csr    = (int2*)    carve((size_t)E * 8);
    _Float16* Wt_in  = (_Float16*)carve(384 * 128 * 2);
    _Float16* Wt_h   = (_Float16*)carve(384 * 128 * 2);
    int*      deg    = (int*)     carve((size_t)N * 4);
    int*      rowptr = (int*)     carve((size_t)(N + 1) * 4);
    int*      fill   = (int*)     carve((size_t)N * 4);
    int*      partial= (int*)     carve(256 * 4);
    float*    ps     = (float*)   carve((size_t)CS_BLOCKS * 128 * 4);
    float*    pss    = (float*)   carve((size_t)CS_BLOCKS * 128 * 4);
    float*    meanp  = (float*)   carve(128 * 4);
    float*    rstdp  = (float*)   carve(128 * 4);
    float*    wsum   = (float*)   carve((size_t)N * 4);
    float*    a1     = (float*)   carve((size_t)N * 4);
    float*    dpart  = (float*)   carve((size_t)N * 4);

    const long long totNF = (long long)N * 128;
    const int nodeWaveBlocks = (N + 3) / 4;
    const int aggBlocks = (N + 7) / 8;
    const int eBlocks = (E + 255) / 256;
    const int nBlocks = (N + 255) / 256;
    const int nb = (N + 1023) / 1024;
    const int wBlocks = (384 * 128 + 255) / 256;

    hipMemsetAsync(deg, 0, (size_t)N * 4, stream);

    // ---- CSR build + weight conversion ----
    hist_kernel<<<eBlocks, 256, 0, stream>>>(dstp, deg, E);
    scan_pass1<<<nb, 256, 0, stream>>>(deg, N, partial);
    scan_pass2<<<1, 256, 0, stream>>>(partial, nb);
    scan_pass3<<<nb, 256, 0, stream>>>(deg, N, partial, rowptr, fill, E);
    csr_fill_kernel<<<eBlocks, 256, 0, stream>>>(srcp, dstp, ew, fill, csr, E);
    wsum_csr_kernel<<<nBlocks, 256, 0, stream>>>(rowptr, csr, wsum, N);
    convert_weights_kernel<<<wBlocks, 256, 0, stream>>>(W1_in, W2_in, W3_in, Wt_in);
    convert_weights_kernel<<<wBlocks, 256, 0, stream>>>(W1_h, W2_h, W3_h, Wt_h);

    // ---- input standardization (coalesced partials, no atomics) ----
    colstats_kernel<<<CS_BLOCKS, 256, 0, stream>>>(x, N, ps, pss);
    reduce_stats_kernel<<<1, 256, 0, stream>>>(ps, pss, N, meanp, rstdp);
    standardize_kernel<<<(int)((totNF + 255) / 256), 256, 0, stream>>>(x, meanp, rstdp, buf_h, totNF);

    const int nTiles = (N + 63) / 64;
    const int gemmGrid = (nTiles < 512) ? nTiles : 512;

    // ---- layer 1 ----
    gemm_mfma_kernel<<<gemmGrid, 256, 0, stream>>>(buf_h, N, nTiles, Wt_in, b1_in, b3_in, wsum, buf_a, buf_d);
    aggregate_ln_kernel<<<aggBlocks, 256, 0, stream>>>(rowptr, csr, buf_a, buf_d, g1, beta1, buf_h, N, E);

    // ---- layers 2..3 ----
    for (int l = 0; l < 2; ++l) {
        gemm_mfma_kernel<<<gemmGrid, 256, 0, stream>>>(buf_h, N, nTiles, Wt_h, b1_h, b3_h, wsum, buf_a, buf_d);
        aggregate_ln_kernel<<<aggBlocks, 256, 0, stream>>>(rowptr, csr, buf_a, buf_d, g2, beta2, buf_h, N, E);
    }

    // ---- output layer ----
    out_gemv_kernel<<<nodeWaveBlocks, 256, 0, stream>>>(buf_h, N, W1_o, b1_o, W2_o, W3_o, b3_o, wsum, a1, dpart);
    gather_out_kernel<<<nBlocks, 256, 0, stream>>>(rowptr, csr, a1, dpart, (float*)d_out, N);
}

// Round 8
// 370.988 us; speedup vs baseline: 3.6281x; 1.0291x over previous
//
#include <hip/hip_runtime.h>
#include <hip/hip_bf16.h>
#include <math.h>

// ---------------------------------------------------------------------------
// GNN_72103910966081: 4-layer LEConv GNN, N=50000, E=600000, D=128.
// Round 8: aggregate_ln third geometry — 1 node/wave, 4 edge-groups x 16
// lanes x f16x8: each gather instr = 4 edge-rows (1KB), no degree-pairing
// waste (R7's max(degA,degB) pairing gave back ~25us).
// ---------------------------------------------------------------------------

typedef _Float16 f16x8 __attribute__((ext_vector_type(8)));
typedef _Float16 f16x4 __attribute__((ext_vector_type(4)));
typedef float f32x4 __attribute__((ext_vector_type(4)));

#define LSTRIDE 136   // halves per LDS row: 128 + 8 (16B-aligned, breaks 2^k banks)

__device__ inline float wave_reduce_sum(float v) {
    #pragma unroll
    for (int off = 32; off > 0; off >>= 1)
        v += __shfl_xor(v, off, 64);
    return v;
}

// ===================== CSR build =====================

__global__ __launch_bounds__(256) void hist_kernel(
    const int* __restrict__ dst, int* __restrict__ deg, int E)
{
    int e = blockIdx.x * 256 + threadIdx.x;
    if (e < E) atomicAdd(&deg[dst[e]], 1);
}

__global__ __launch_bounds__(256) void scan_pass1(
    const int* __restrict__ deg, int N, int* __restrict__ partial)
{
    __shared__ int sh[256];
    int t = threadIdx.x;
    int base = blockIdx.x * 1024 + t * 4;
    int s = 0;
    #pragma unroll
    for (int i = 0; i < 4; ++i) { int idx = base + i; if (idx < N) s += deg[idx]; }
    sh[t] = s; __syncthreads();
    for (int off = 128; off > 0; off >>= 1) {
        if (t < off) sh[t] += sh[t + off];
        __syncthreads();
    }
    if (t == 0) partial[blockIdx.x] = sh[0];
}

__global__ __launch_bounds__(256) void scan_pass2(int* __restrict__ partial, int nb)
{
    __shared__ int sh[256];
    int t = threadIdx.x;
    sh[t] = (t < nb) ? partial[t] : 0;
    __syncthreads();
    for (int off = 1; off < 256; off <<= 1) {
        int x = sh[t];
        if (t >= off) x += sh[t - off];
        __syncthreads();
        sh[t] = x;
        __syncthreads();
    }
    if (t < nb) partial[t] = (t > 0) ? sh[t - 1] : 0;   // exclusive
}

__global__ __launch_bounds__(256) void scan_pass3(
    const int* __restrict__ deg, int N, const int* __restrict__ partial,
    int* __restrict__ rowptr, int* __restrict__ fill, int E)
{
    __shared__ int sh[256];
    int t = threadIdx.x;
    int base = blockIdx.x * 1024 + t * 4;
    int v[4]; int s = 0;
    #pragma unroll
    for (int i = 0; i < 4; ++i) { int idx = base + i; v[i] = (idx < N) ? deg[idx] : 0; s += v[i]; }
    sh[t] = s; __syncthreads();
    for (int off = 1; off < 256; off <<= 1) {
        int x = sh[t];
        if (t >= off) x += sh[t - off];
        __syncthreads();
        sh[t] = x;
        __syncthreads();
    }
    int off0 = partial[blockIdx.x] + ((t > 0) ? sh[t - 1] : 0);
    #pragma unroll
    for (int i = 0; i < 4; ++i) {
        int idx = base + i;
        if (idx < N) { rowptr[idx] = off0; fill[idx] = off0; off0 += v[i]; }
    }
    if (blockIdx.x == 0 && t == 0) rowptr[N] = E;
}

__global__ __launch_bounds__(256) void csr_fill_kernel(
    const int* __restrict__ src, const int* __restrict__ dst,
    const float* __restrict__ ew, int* __restrict__ fill,
    int2* __restrict__ csr, int E)
{
    int e = blockIdx.x * 256 + threadIdx.x;
    if (e >= E) return;
    int d = dst[e];
    int pos = atomicAdd(&fill[d], 1);
    csr[pos] = make_int2(src[e], __float_as_int(ew[e]));
}

__global__ __launch_bounds__(256) void wsum_csr_kernel(
    const int* __restrict__ rowptr, const int2* __restrict__ csr,
    float* __restrict__ wsum, int N)
{
    int n = blockIdx.x * 256 + threadIdx.x;
    if (n >= N) return;
    int b = rowptr[n], en = rowptr[n + 1];
    float s = 0.f;
    for (int e = b; e < en; ++e) s += __int_as_float(csr[e].y);
    wsum[n] = s;
}

// ===================== weight convert+transpose (fp32 [k][n] -> fp16 [n][k]) ==

__global__ __launch_bounds__(256) void convert_weights_kernel(
    const float* __restrict__ W1, const float* __restrict__ W2,
    const float* __restrict__ W3, _Float16* __restrict__ Wt)
{
    int idx = blockIdx.x * 256 + threadIdx.x;   // over 384*128
    if (idx >= 384 * 128) return;
    int n = idx >> 7, k = idx & 127;
    const float* W = (n < 128) ? W1 : (n < 256) ? W2 : W3;
    int c = n & 127;
    Wt[idx] = (_Float16)W[k * 128 + c];
}

// ===================== input standardization (coalesced, partials) =========

#define CS_BLOCKS 512

__global__ __launch_bounds__(256) void colstats_kernel(
    const float* __restrict__ x, int N,
    float* __restrict__ ps, float* __restrict__ pss)   // [CS_BLOCKS][128] each
{
    __shared__ float shs[256][4];
    __shared__ float shq[256][4];
    int t = threadIdx.x;
    int g = t >> 5;
    int c = t & 31;
    const float4* xv = (const float4*)x;    // row stride 32
    float s0=0.f,s1=0.f,s2=0.f,s3=0.f, q0=0.f,q1=0.f,q2=0.f,q3=0.f;
    for (int r = blockIdx.x * 8 + g; r < N; r += CS_BLOCKS * 8) {
        float4 v = xv[(size_t)r * 32 + c];
        s0 += v.x; s1 += v.y; s2 += v.z; s3 += v.w;
        q0 += v.x*v.x; q1 += v.y*v.y; q2 += v.z*v.z; q3 += v.w*v.w;
    }
    shs[t][0]=s0; shs[t][1]=s1; shs[t][2]=s2; shs[t][3]=s3;
    shq[t][0]=q0; shq[t][1]=q1; shq[t][2]=q2; shq[t][3]=q3;
    __syncthreads();
    if (t < 32) {
        float S[4] = {0,0,0,0}, Q[4] = {0,0,0,0};
        #pragma unroll
        for (int gg = 0; gg < 8; ++gg) {
            #pragma unroll
            for (int i = 0; i < 4; ++i) {
                S[i] += shs[t + 32*gg][i];
                Q[i] += shq[t + 32*gg][i];
            }
        }
        #pragma unroll
        for (int i = 0; i < 4; ++i) {
            ps [blockIdx.x * 128 + t*4 + i] = S[i];
            pss[blockIdx.x * 128 + t*4 + i] = Q[i];
        }
    }
}

__global__ __launch_bounds__(256) void reduce_stats_kernel(
    const float* __restrict__ ps, const float* __restrict__ pss, int N,
    float* __restrict__ mean, float* __restrict__ rstd)
{
    __shared__ float sh[256];
    int t = threadIdx.x;           // 256
    int f = t & 127;
    const float* src = (t >= 128) ? pss : ps;
    float s = 0.f;
    for (int r = 0; r < CS_BLOCKS; ++r) s += src[r * 128 + f];
    sh[t] = s;
    __syncthreads();
    if (t < 128) {
        float sum = sh[t], sumsq = sh[t + 128];
        float m = sum / (float)N;
        float var = (sumsq - sum * sum / (float)N) / (float)(N - 1);  // ddof=1
        var = fmaxf(var, 0.f);
        mean[t] = m;
        rstd[t] = 1.f / (sqrtf(var) + 1e-6f);
    }
}

__global__ __launch_bounds__(256) void standardize_kernel(
    const float* __restrict__ x, const float* __restrict__ mean,
    const float* __restrict__ rstd, _Float16* __restrict__ out, long long total)
{
    long long i = (long long)blockIdx.x * blockDim.x + threadIdx.x;
    if (i >= total) return;
    int f = (int)(i & 127);
    out[i] = (_Float16)((x[i] - mean[f]) * rstd[f]);
}

// ===================== MFMA fused GEMM (persistent, B in registers) ========

__global__ __launch_bounds__(256, 2) void gemm_mfma_kernel(
    const _Float16* __restrict__ h, int N, int nTiles,
    const _Float16* __restrict__ Wt,
    const float* __restrict__ b1,
    const float* __restrict__ b3,
    const float* __restrict__ wsum,
    _Float16* __restrict__ out_a, _Float16* __restrict__ out_d)
{
    __shared__ _Float16 ldsS[64 * LSTRIDE];   // staged A tile
    __shared__ _Float16 lds_a[64 * LSTRIDE];  // epilogue a
    __shared__ _Float16 lds_d[64 * LSTRIDE];  // epilogue d

    int t = threadIdx.x;
    int wave = t >> 6;
    int lane = t & 63;
    int quad = lane >> 4;     // 0..3
    int c16  = lane & 15;     // 0..15

    // ---- B fragments: 6 n-tiles x 4 k-steps, in registers for the kernel's life
    const f16x8* wv = (const f16x8*)Wt;  // row (n) stride 16 chunks
    int ntl[6] = {2*wave, 2*wave+1, 8+2*wave, 9+2*wave, 16+2*wave, 17+2*wave};
    f16x8 bfrag[6][4];
    #pragma unroll
    for (int j = 0; j < 6; ++j) {
        int nrow = ntl[j] * 16 + c16;
        #pragma unroll
        for (int s = 0; s < 4; ++s)
            bfrag[j][s] = wv[(size_t)nrow * 16 + s * 4 + quad];
    }
    float bb1[2], bb3[2];
    #pragma unroll
    for (int j = 0; j < 2; ++j) {
        int col = (2*wave + j) * 16 + c16;
        bb1[j] = b1[col];
        bb3[j] = b3[col];
    }

    const f16x8* hv = (const f16x8*)h;   // row stride 16 chunks
    f16x8* oa = (f16x8*)out_a;
    f16x8* od = (f16x8*)out_d;

    for (int tile = blockIdx.x; tile < nTiles; tile += gridDim.x) {
        int row0 = tile * 64;

        // ---- stage A tile (64 rows x 256B) into LDS, fully coalesced
        #pragma unroll
        for (int i = 0; i < 4; ++i) {
            int idx = i * 256 + t;        // 0..1023
            int row = idx >> 4;
            int chunk = idx & 15;
            int grow = row0 + row;
            if (grow >= N) grow = N - 1;  // clamp; per-row results discarded later
            *(f16x8*)&ldsS[row * LSTRIDE + chunk * 8] = hv[(size_t)grow * 16 + chunk];
        }
        __syncthreads();

        // ---- 4 row-groups of 16 rows each
        #pragma unroll
        for (int r = 0; r < 4; ++r) {
            f16x8 afrag[4];
            #pragma unroll
            for (int s = 0; s < 4; ++s)
                afrag[s] = *(const f16x8*)&ldsS[(r*16 + c16) * LSTRIDE + (s*4 + quad) * 8];

            f32x4 acc[6];
            #pragma unroll
            for (int j = 0; j < 6; ++j) acc[j] = (f32x4){0.f, 0.f, 0.f, 0.f};
            #pragma unroll
            for (int s = 0; s < 4; ++s) {
                #pragma unroll
                for (int j = 0; j < 6; ++j)
                    acc[j] = __builtin_amdgcn_mfma_f32_16x16x32_f16(afrag[s], bfrag[j][s], acc[j], 0, 0, 0);
            }

            // epilogue -> LDS (C/D layout: col=c16, row=quad*4+reg)
            float wsv[4];
            #pragma unroll
            for (int reg = 0; reg < 4; ++reg) {
                int gr = row0 + r*16 + quad*4 + reg;
                wsv[reg] = wsum[(gr < N) ? gr : (N - 1)];
            }
            #pragma unroll
            for (int j = 0; j < 2; ++j) {
                int col = (2*wave + j) * 16 + c16;
                #pragma unroll
                for (int reg = 0; reg < 4; ++reg) {
                    int lr = r*16 + quad*4 + reg;
                    lds_a[lr * LSTRIDE + col] = (_Float16)(acc[j][reg] + bb1[j]);
                    lds_d[lr * LSTRIDE + col] =
                        (_Float16)(acc[4+j][reg] + bb3[j] - wsv[reg] * acc[2+j][reg]);
                }
            }
        }
        __syncthreads();

        // ---- coalesced stores (64 rows x 16 chunks of 16B, both buffers)
        #pragma unroll
        for (int i = 0; i < 4; ++i) {
            int idx = i * 256 + t;
            int row = idx >> 4;
            int c8  = idx & 15;
            int grow = row0 + row;
            if (grow < N) {
                f16x8 va = *(const f16x8*)&lds_a[row * LSTRIDE + c8 * 8];
                oa[(size_t)grow * 16 + c8] = va;
                f16x8 vd = *(const f16x8*)&lds_d[row * LSTRIDE + c8 * 8];
                od[(size_t)grow * 16 + c8] = vd;
            }
        }
        __syncthreads();   // protect ldsS/lds_* before next iteration's writes
    }
}

// ===================== fused gather + LN + leaky =====================
// 1 node per wave; 4 edge-groups x 16 lanes x f16x8 (16B/lane).
// One gather instruction = 4 edge-rows (4 x 256B). No cross-node pairing.

__global__ __launch_bounds__(256) void aggregate_ln_kernel(
    const int* __restrict__ rowptr, const int2* __restrict__ csr,
    const _Float16* __restrict__ a, const _Float16* __restrict__ d,
    const float* __restrict__ g, const float* __restrict__ beta,
    _Float16* __restrict__ out, int N)
{
    int wave = threadIdx.x >> 6;
    int lane = threadIdx.x & 63;
    int grp  = lane >> 4;        // 0..3: edge group
    int l    = lane & 15;        // feature chunk: cols 8l..8l+7
    int node = blockIdx.x * 4 + wave;
    if (node >= N) return;
    int b = rowptr[node], en = rowptr[node + 1];
    int deg = en - b;

    const f16x8* av = (const f16x8*)a;   // row stride 16 chunks
    float acc[8] = {0,0,0,0,0,0,0,0};

    int nk = (deg + 3) >> 2;             // edge e = b + k*4 + grp
    int k = 0;
    for (; k + 4 <= nk; k += 4) {        // 16 edge-rows in flight
        int2 p[4];
        #pragma unroll
        for (int j = 0; j < 4; ++j) {
            int idx = b + (k + j) * 4 + grp;
            int idc = (idx < en) ? idx : b;     // clamp to hot row
            p[j] = csr[idc];
            if (idx >= en) p[j].y = 0;
        }
        f16x8 v[4];
        #pragma unroll
        for (int j = 0; j < 4; ++j)
            v[j] = av[(size_t)p[j].x * 16 + l];
        #pragma unroll
        for (int j = 0; j < 4; ++j) {
            float w = __int_as_float(p[j].y);
            #pragma unroll
            for (int i = 0; i < 8; ++i) acc[i] += w * (float)v[j][i];
        }
    }
    for (; k < nk; ++k) {
        int idx = b + k * 4 + grp;
        int idc = (idx < en) ? idx : b;
        int2 p = csr[idc];
        if (idx >= en) p.y = 0;
        f16x8 v = av[(size_t)p.x * 16 + l];
        float w = __int_as_float(p.y);
        #pragma unroll
        for (int i = 0; i < 8; ++i) acc[i] += w * (float)v[i];
    }

    // combine the 4 edge groups (lanes differing in bits 4,5)
    #pragma unroll
    for (int i = 0; i < 8; ++i) {
        acc[i] += __shfl_xor(acc[i], 16, 64);
        acc[i] += __shfl_xor(acc[i], 32, 64);
    }

    f16x8 dv = ((const f16x8*)d)[(size_t)node * 16 + l];
    float v[8];
    float s = 0.f, ss = 0.f;
    #pragma unroll
    for (int i = 0; i < 8; ++i) {
        v[i] = acc[i] + (float)dv[i];
        s += v[i]; ss += v[i] * v[i];
    }
    // LN reduce over the 16 feature lanes
    #pragma unroll
    for (int off = 1; off <= 8; off <<= 1) {
        s  += __shfl_xor(s,  off, 64);
        ss += __shfl_xor(ss, off, 64);
    }
    float mean = s * (1.f / 128.f);
    float var = ss * (1.f / 128.f) - mean * mean;
    float rstd = rsqrtf(var + 1e-5f);

    const float4* gv4 = (const float4*)g;
    const float4* bv4 = (const float4*)beta;
    float4 ga = gv4[l*2], gb = gv4[l*2+1];
    float4 ba = bv4[l*2], bb = bv4[l*2+1];
    float go[8] = {ga.x,ga.y,ga.z,ga.w,gb.x,gb.y,gb.z,gb.w};
    float bo[8] = {ba.x,ba.y,ba.z,ba.w,bb.x,bb.y,bb.z,bb.w};
    f16x8 ov;
    #pragma unroll
    for (int i = 0; i < 8; ++i) {
        float o = (v[i] - mean) * rstd * go[i] + bo[i];
        o = o >= 0.f ? o : 0.1f * o;
        ov[i] = (_Float16)o;
    }
    if (grp == 0)
        ((f16x8*)out)[(size_t)node * 16 + l] = ov;
}

// ===================== output layer (D_OUT=1) =====================

__global__ __launch_bounds__(256) void out_gemv_kernel(
    const _Float16* __restrict__ h, int N,
    const float* __restrict__ W1, const float* __restrict__ b1,
    const float* __restrict__ W2,
    const float* __restrict__ W3, const float* __restrict__ b3,
    const float* __restrict__ wsum,
    float* __restrict__ a1, float* __restrict__ dpart)
{
    int wave = threadIdx.x >> 6;
    int lane = threadIdx.x & 63;
    int node = blockIdx.x * 4 + wave;
    if (node >= N) return;
    const _Float16* row = h + (size_t)node * 128;
    float h0 = (float)row[lane], h1 = (float)row[lane + 64];
    float s1 = wave_reduce_sum(h0 * W1[lane] + h1 * W1[lane + 64]);
    float s2 = wave_reduce_sum(h0 * W2[lane] + h1 * W2[lane + 64]);
    float s3 = wave_reduce_sum(h0 * W3[lane] + h1 * W3[lane + 64]);
    if (lane == 0) {
        a1[node] = s1 + b1[0];
        dpart[node] = s3 + b3[0] - wsum[node] * s2;
    }
}

__global__ __launch_bounds__(256) void gather_out_kernel(
    const int* __restrict__ rowptr, const int2* __restrict__ csr,
    const float* __restrict__ a1, const float* __restrict__ dpart,
    float* __restrict__ out, int N)
{
    int n = blockIdx.x * 256 + threadIdx.x;
    if (n >= N) return;
    int b = rowptr[n], en = rowptr[n + 1];
    float s = dpart[n];
    int e = b;
    for (; e + 4 <= en; e += 4) {
        int2 p0 = csr[e], p1 = csr[e+1], p2 = csr[e+2], p3 = csr[e+3];
        float x0 = a1[p0.x], x1 = a1[p1.x], x2 = a1[p2.x], x3 = a1[p3.x];
        s += __int_as_float(p0.y) * x0 + __int_as_float(p1.y) * x1
           + __int_as_float(p2.y) * x2 + __int_as_float(p3.y) * x3;
    }
    for (; e < en; ++e) {
        int2 p = csr[e];
        s += __int_as_float(p.y) * a1[p.x];
    }
    out[n] = 1.f / (1.f + expf(-s));
}

// ---------------------------------------------------------------------------
extern "C" void kernel_launch(void* const* d_in, const int* in_sizes, int n_in,
                              void* d_out, int out_size, void* d_ws, size_t ws_size,
                              hipStream_t stream)
{
    const float* x     = (const float*)d_in[0];
    const float* ew    = (const float*)d_in[1];
    const float* W1_in = (const float*)d_in[2];
    const float* b1_in = (const float*)d_in[3];
    const float* W2_in = (const float*)d_in[4];
    const float* W3_in = (const float*)d_in[5];
    const float* b3_in = (const float*)d_in[6];
    const float* W1_h  = (const float*)d_in[7];
    const float* b1_h  = (const float*)d_in[8];
    const float* W2_h  = (const float*)d_in[9];
    const float* W3_h  = (const float*)d_in[10];
    const float* b3_h  = (const float*)d_in[11];
    const float* W1_o  = (const float*)d_in[12];
    const float* b1_o  = (const float*)d_in[13];
    const float* W2_o  = (const float*)d_in[14];
    const float* W3_o  = (const float*)d_in[15];
    const float* b3_o  = (const float*)d_in[16];
    const float* g1    = (const float*)d_in[17];
    const float* beta1 = (const float*)d_in[18];
    const float* g2    = (const float*)d_in[19];
    const float* beta2 = (const float*)d_in[20];
    const int*   eidx  = (const int*)d_in[21];

    const int N = in_sizes[0] / 128;
    const int E = in_sizes[1];
    const int* srcp = eidx;
    const int* dstp = eidx + E;

    // ---- workspace carve-out (256B-aligned chunks) ----
    size_t off = 0;
    auto carve = [&](size_t nbytes) -> void* {
        void* p = (char*)d_ws + off;
        off += (nbytes + 255) & ~(size_t)255;
        return p;
    };
    _Float16* buf_h  = (_Float16*)carve((size_t)N * 128 * 2);
    _Float16* buf_a  = (_Float16*)carve((size_t)N * 128 * 2);
    _Float16* buf_d  = (_Float16*)carve((size_t)N * 128 * 2);
    int2*     csr    = (int2*)    carve((size_t)E * 8);
    _Float16* Wt_in  = (_Float16*)carve(384 * 128 * 2);
    _Float16* Wt_h   = (_Float16*)carve(384 * 128 * 2);
    int*      deg    = (int*)     carve((size_t)N * 4);
    int*      rowptr = (int*)     carve((size_t)(N + 1) * 4);
    int*      fill   = (int*)     carve((size_t)N * 4);
    int*      partial= (int*)     carve(256 * 4);
    float*    ps     = (float*)   carve((size_t)CS_BLOCKS * 128 * 4);
    float*    pss    = (float*)   carve((size_t)CS_BLOCKS * 128 * 4);
    float*    meanp  = (float*)   carve(128 * 4);
    float*    rstdp  = (float*)   carve(128 * 4);
    float*    wsum   = (float*)   carve((size_t)N * 4);
    float*    a1     = (float*)   carve((size_t)N * 4);
    float*    dpart  = (float*)   carve((size_t)N * 4);

    const long long totNF = (long long)N * 128;
    const int nodeWaveBlocks = (N + 3) / 4;
    const int eBlocks = (E + 255) / 256;
    const int nBlocks = (N + 255) / 256;
    const int nb = (N + 1023) / 1024;
    const int wBlocks = (384 * 128 + 255) / 256;

    hipMemsetAsync(deg, 0, (size_t)N * 4, stream);

    // ---- CSR build + weight conversion ----
    hist_kernel<<<eBlocks, 256, 0, stream>>>(dstp, deg, E);
    scan_pass1<<<nb, 256, 0, stream>>>(deg, N, partial);
    scan_pass2<<<1, 256, 0, stream>>>(partial, nb);
    scan_pass3<<<nb, 256, 0, stream>>>(deg, N, partial, rowptr, fill, E);
    csr_fill_kernel<<<eBlocks, 256, 0, stream>>>(srcp, dstp, ew, fill, csr, E);
    wsum_csr_kernel<<<nBlocks, 256, 0, stream>>>(rowptr, csr, wsum, N);
    convert_weights_kernel<<<wBlocks, 256, 0, stream>>>(W1_in, W2_in, W3_in, Wt_in);
    convert_weights_kernel<<<wBlocks, 256, 0, stream>>>(W1_h, W2_h, W3_h, Wt_h);

    // ---- input standardization (coalesced partials, no atomics) ----
    colstats_kernel<<<CS_BLOCKS, 256, 0, stream>>>(x, N, ps, pss);
    reduce_stats_kernel<<<1, 256, 0, stream>>>(ps, pss, N, meanp, rstdp);
    standardize_kernel<<<(int)((totNF + 255) / 256), 256, 0, stream>>>(x, meanp, rstdp, buf_h, totNF);

    const int nTiles = (N + 63) / 64;
    const int gemmGrid = (nTiles < 512) ? nTiles : 512;

    // ---- layer 1 ----
    gemm_mfma_kernel<<<gemmGrid, 256, 0, stream>>>(buf_h, N, nTiles, Wt_in, b1_in, b3_in, wsum, buf_a, buf_d);
    aggregate_ln_kernel<<<nodeWaveBlocks, 256, 0, stream>>>(rowptr, csr, buf_a, buf_d, g1, beta1, buf_h, N);

    // ---- layers 2..3 ----
    for (int l = 0; l < 2; ++l) {
        gemm_mfma_kernel<<<gemmGrid, 256, 0, stream>>>(buf_h, N, nTiles, Wt_h, b1_h, b3_h, wsum, buf_a, buf_d);
        aggregate_ln_kernel<<<nodeWaveBlocks, 256, 0, stream>>>(rowptr, csr, buf_a, buf_d, g2, beta2, buf_h, N);
    }

    // ---- output layer ----
    out_gemv_kernel<<<nodeWaveBlocks, 256, 0, stream>>>(buf_h, N, W1_o, b1_o, W2_o, W3_o, b3_o, wsum, a1, dpart);
    gather_out_kernel<<<nBlocks, 256, 0, stream>>>(rowptr, csr, a1, dpart, (float*)d_out, N);
}